// Round 1
// baseline (468.272 us; speedup 1.0000x reference)
//
#include <hip/hip_runtime.h>
#include <cstdint>
#include <cstddef>

// ---------- types ----------
typedef __bf16 bf16x8 __attribute__((ext_vector_type(8)));
typedef float  f32x4  __attribute__((ext_vector_type(4)));
typedef unsigned short us8 __attribute__((ext_vector_type(8)));
typedef unsigned short us4 __attribute__((ext_vector_type(4)));

__device__ __forceinline__ unsigned short f2bf(float f) {
  union { float f; unsigned u; } v; v.f = f;
  unsigned r = v.u + 0x7FFFu + ((v.u >> 16) & 1u);
  return (unsigned short)(r >> 16);
}
__device__ __forceinline__ float b2f(unsigned short h) {
  union { unsigned u; float f; } v; v.u = ((unsigned)h) << 16;
  return v.f;
}
__device__ __forceinline__ f32x4 mfma16(bf16x8 a, bf16x8 b, f32x4 c) {
  return __builtin_amdgcn_mfma_f32_16x16x32_bf16(a, b, c, 0, 0, 0);
}

// ---------- misc prep: bias concat, rope tables, zero-pad ----------
__global__ void prep_misc_kernel(const float* __restrict__ b_qkv,
                                 const float* __restrict__ b_kpos,
                                 const float* __restrict__ b_qup,
                                 const float* __restrict__ b_qpos,
                                 float* __restrict__ bias1,
                                 float* __restrict__ bias2q,
                                 float* __restrict__ costab,
                                 float* __restrict__ sintab,
                                 unsigned short* __restrict__ wB1pad) {
  int i = blockIdx.x * 256 + threadIdx.x;   // grid covers 131072
  if (i < 65536) {                          // 2048 x 32 rope tables
    int s = i >> 5, f = i & 31;
    float inv = powf(50000.0f, -(float)f / 32.0f);
    float a = (float)s * inv;
    costab[i] = cosf(a);
    sintab[i] = sinf(a);
  }
  if (i < 1664) bias1[i] = (i < 1536) ? b_qkv[i] : (i < 1600 ? b_kpos[i - 1536] : 0.0f);
  if (i < 3072) bias2q[i] = (i < 2048) ? b_qup[i] : b_qpos[i - 2048];
  if (i < 131072) wB1pad[i] = 0;            // rows 1600..1663 of wB1
}

// ---------- x fp32 -> bf16 ----------
__global__ void convx_kernel(const float* __restrict__ in,
                             unsigned short* __restrict__ out, int n4) {
  int i = blockIdx.x * 256 + threadIdx.x;
  if (i < n4) {
    float4 v = ((const float4*)in)[i];
    us4 o;
    o[0] = f2bf(v.x); o[1] = f2bf(v.y); o[2] = f2bf(v.z); o[3] = f2bf(v.w);
    ((us4*)out)[i] = o;
  }
}

// ---------- weight transpose + convert: out[c*ldo + r] = bf16(in[r*ldin + c]) ----------
__global__ void tconv_kernel(const float* __restrict__ in, int ldin,
                             unsigned short* __restrict__ out, int ldo) {
  __shared__ float tile[32][33];
  int c0 = blockIdx.x * 32, r0 = blockIdx.y * 32;
  int tx = threadIdx.x & 31, ty = threadIdx.x >> 5;
  for (int j = 0; j < 4; ++j)
    tile[ty + j * 8][tx] = in[(size_t)(r0 + ty + j * 8) * ldin + c0 + tx];
  __syncthreads();
  for (int j = 0; j < 4; ++j)
    out[(size_t)(c0 + ty + j * 8) * ldo + r0 + tx] = f2bf(tile[tx][ty + j * 8]);
}

// ---------- GEMM: C[M,N] = A[M,K](bf16,row-major,lda) * Bt[N,K](bf16,row-major,ldb)^T + bias ----------
// 128x128 tile, 4 waves (2x2), BK=32, reg-staged LDS with +8 pad.
template <int OUT_F32>
__global__ __launch_bounds__(256, 2)
void gemm_bt_kernel(const unsigned short* __restrict__ A, int lda,
                    const unsigned short* __restrict__ Bt, int ldb,
                    void* __restrict__ Cout, int ldc,
                    const float* __restrict__ bias, int K) {
  __shared__ unsigned short Alds[128][40];
  __shared__ unsigned short Blds[128][40];
  int tid = threadIdx.x;
  int wave = tid >> 6, lane = tid & 63;
  int g = lane >> 4, r = lane & 15;
  int wr = wave >> 1, wc = wave & 1;
  long brow = (long)blockIdx.y * 128, bcol = (long)blockIdx.x * 128;

  int row0 = tid >> 2, seg0 = tid & 3;   // slot j=0: rows 0..63; j=1: rows 64..127
  int row1 = row0 + 64;
  const unsigned short* Ag0 = A + (brow + row0) * (long)lda + seg0 * 8;
  const unsigned short* Ag1 = A + (brow + row1) * (long)lda + seg0 * 8;
  const unsigned short* Bg0 = Bt + (bcol + row0) * (long)ldb + seg0 * 8;
  const unsigned short* Bg1 = Bt + (bcol + row1) * (long)ldb + seg0 * 8;

  f32x4 acc[4][4];
  for (int mi = 0; mi < 4; ++mi)
    for (int ni = 0; ni < 4; ++ni)
      acc[mi][ni] = f32x4{0.f, 0.f, 0.f, 0.f};

  us8 ra0 = *(const us8*)(Ag0);
  us8 ra1 = *(const us8*)(Ag1);
  us8 rb0 = *(const us8*)(Bg0);
  us8 rb1 = *(const us8*)(Bg1);

  for (int k0 = 0; k0 < K; k0 += 32) {
    *(us8*)&Alds[row0][seg0 * 8] = ra0;
    *(us8*)&Alds[row1][seg0 * 8] = ra1;
    *(us8*)&Blds[row0][seg0 * 8] = rb0;
    *(us8*)&Blds[row1][seg0 * 8] = rb1;
    __syncthreads();
    int k1 = k0 + 32;
    if (k1 < K) {
      ra0 = *(const us8*)(Ag0 + k1);
      ra1 = *(const us8*)(Ag1 + k1);
      rb0 = *(const us8*)(Bg0 + k1);
      rb1 = *(const us8*)(Bg1 + k1);
    }
    bf16x8 af[4], bfv[4];
    for (int mi = 0; mi < 4; ++mi)
      af[mi] = *(const bf16x8*)&Alds[wr * 64 + mi * 16 + r][g * 8];
    for (int ni = 0; ni < 4; ++ni)
      bfv[ni] = *(const bf16x8*)&Blds[wc * 64 + ni * 16 + r][g * 8];
    for (int mi = 0; mi < 4; ++mi)
      for (int ni = 0; ni < 4; ++ni)
        acc[mi][ni] = mfma16(af[mi], bfv[ni], acc[mi][ni]);
    __syncthreads();
  }

  for (int mi = 0; mi < 4; ++mi)
    for (int ni = 0; ni < 4; ++ni) {
      long col = bcol + wc * 64 + ni * 16 + r;
      float bv = bias ? bias[col] : 0.0f;
      long rowb = brow + wr * 64 + mi * 16 + g * 4;
      for (int i = 0; i < 4; ++i) {
        float v = acc[mi][ni][i] + bv;
        if (OUT_F32)
          ((float*)Cout)[(rowb + i) * (long)ldc + col] = v;
        else
          ((unsigned short*)Cout)[(rowb + i) * (long)ldc + col] = f2bf(v);
      }
    }
}

// ---------- assemble q,k with RoPE ----------
// q/k layout: [B,NH,S,192]; d<128 = nope part; d in [128,192) = rope'd pos part
__global__ void assemble_qk_kernel(const unsigned short* __restrict__ tmp_q,
                                   const unsigned short* __restrict__ tmp_k,
                                   const unsigned short* __restrict__ lat_ext,
                                   const float* __restrict__ costab,
                                   const float* __restrict__ sintab,
                                   unsigned short* __restrict__ qb,
                                   unsigned short* __restrict__ kb) {
  int idx = blockIdx.x * 256 + threadIdx.x;  // 32*2048*192 exact
  int d = idx % 192;
  int t = idx / 192;
  int s = t & 2047;
  int bh = t >> 11;
  int b = bh >> 4, h = bh & 15;
  size_t qo = ((size_t)bh * 2048 + s) * 192 + d;
  size_t rowA = (size_t)(b * 2048 + s);
  unsigned short qv, kv;
  if (d < 128) {
    qv = tmp_q[rowA * 3072 + h * 128 + d];
    kv = tmp_k[rowA * 2048 + h * 128 + d];
  } else {
    int dp = d - 128;
    int f = dp & 31;
    float c = costab[s * 32 + f], sn = sintab[s * 32 + f];
    int dq = (dp < 32) ? dp + 32 : dp - 32;
    float x1 = b2f(tmp_q[rowA * 3072 + 2048 + h * 64 + dp]);
    float x2 = b2f(tmp_q[rowA * 3072 + 2048 + h * 64 + dq]);
    float qr = (dp < 32) ? (x1 * c - x2 * sn) : (x1 * c + x2 * sn);
    float k1 = b2f(lat_ext[rowA * 1664 + 1536 + dp]);
    float k2 = b2f(lat_ext[rowA * 1664 + 1536 + dq]);
    float kr = (dp < 32) ? (k1 * c - k2 * sn) : (k1 * c + k2 * sn);
    qv = f2bf(qr);
    kv = f2bf(kr);
  }
  qb[qo] = qv;
  kb[qo] = kv;
}

// ---------- V transpose: tmp_v[B*S, NH*128] -> vT[B,NH,128,S] ----------
__global__ void transpose_v_kernel(const unsigned short* __restrict__ tmp_v,
                                   unsigned short* __restrict__ vT) {
  __shared__ unsigned short tile[32][33];
  int s0 = blockIdx.x * 32, d0 = blockIdx.y * 32, bh = blockIdx.z;
  int b = bh >> 4, h = bh & 15;
  int tx = threadIdx.x & 31, ty = threadIdx.x >> 5;
  const unsigned short* in = tmp_v + (size_t)b * 2048 * 2048 + h * 128;
  for (int j = 0; j < 4; ++j)
    tile[ty + j * 8][tx] = in[(size_t)(s0 + ty + j * 8) * 2048 + d0 + tx];
  __syncthreads();
  unsigned short* out = vT + (size_t)bh * 128 * 2048;
  for (int j = 0; j < 4; ++j)
    out[(size_t)(d0 + ty + j * 8) * 2048 + s0 + tx] = tile[tx][ty + j * 8];
}

// ---------- causal flash attention ----------
// grid (32, 16, 2) = (qtile, h, b); 256 threads = 4 waves x 16 q-rows
__global__ __launch_bounds__(256, 2)
void flash_kernel(const unsigned short* __restrict__ qb,
                  const unsigned short* __restrict__ kb,
                  const unsigned short* __restrict__ vT,
                  unsigned short* __restrict__ ob) {
  const int S = 2048;
  int qt = blockIdx.x, h = blockIdx.y, b = blockIdx.z;
  int bh = b * 16 + h;
  int tid = threadIdx.x, wave = tid >> 6, lane = tid & 63;
  int g = lane >> 4, r = lane & 15;
  int qbase = qt * 64;

  const unsigned short* qp = qb + (size_t)bh * S * 192;
  const unsigned short* kp = kb + (size_t)bh * S * 192;
  const unsigned short* vp = vT + (size_t)bh * 128 * S;

  __shared__ unsigned short Klds[32][200];
  __shared__ unsigned short Vlds[128][40];
  __shared__ unsigned short Plds[4][16][40];

  bf16x8 qf[6];
  {
    int qrow = qbase + wave * 16 + r;
    const unsigned short* qr_ = qp + (size_t)qrow * 192 + g * 8;
    for (int c = 0; c < 6; ++c) qf[c] = *(const bf16x8*)(qr_ + c * 32);
  }

  f32x4 acc[8];
  for (int d = 0; d < 8; ++d) acc[d] = f32x4{0.f, 0.f, 0.f, 0.f};
  float m_r[4], l_r[4];
  for (int i = 0; i < 4; ++i) { m_r[i] = -3.0e38f; l_r[i] = 0.f; }

  const float sl2 = 1.44269504f / 13.8564064605510183f;  // log2e / sqrt(192)
  int nchunk = (qbase + 64) >> 5;

  int ks_row[3], ks_seg[3];
  for (int j = 0; j < 3; ++j) {
    int slot = j * 256 + tid;
    ks_row[j] = slot / 24;
    ks_seg[j] = slot - ks_row[j] * 24;
  }

  us8 kreg[3], vreg[2];
  for (int j = 0; j < 3; ++j)
    kreg[j] = *(const us8*)(kp + (size_t)ks_row[j] * 192 + ks_seg[j] * 8);
  for (int j = 0; j < 2; ++j) {
    int slot = j * 256 + tid, row = slot >> 2, seg = slot & 3;
    vreg[j] = *(const us8*)(vp + (size_t)row * S + seg * 8);
  }

  for (int ch = 0; ch < nchunk; ++ch) {
    for (int j = 0; j < 3; ++j)
      *(us8*)&Klds[ks_row[j]][ks_seg[j] * 8] = kreg[j];
    for (int j = 0; j < 2; ++j) {
      int slot = j * 256 + tid, row = slot >> 2, seg = slot & 3;
      *(us8*)&Vlds[row][seg * 8] = vreg[j];
    }
    __syncthreads();
    if (ch + 1 < nchunk) {
      int kv1 = (ch + 1) * 32;
      for (int j = 0; j < 3; ++j)
        kreg[j] = *(const us8*)(kp + (size_t)(kv1 + ks_row[j]) * 192 + ks_seg[j] * 8);
      for (int j = 0; j < 2; ++j) {
        int slot = j * 256 + tid, row = slot >> 2, seg = slot & 3;
        vreg[j] = *(const us8*)(vp + (size_t)row * S + kv1 + seg * 8);
      }
    }
    int kv0 = ch * 32;

    f32x4 sc0 = {0.f, 0.f, 0.f, 0.f}, sc1 = {0.f, 0.f, 0.f, 0.f};
    for (int c = 0; c < 6; ++c) {
      bf16x8 kf0 = *(const bf16x8*)&Klds[r][c * 32 + g * 8];
      sc0 = mfma16(qf[c], kf0, sc0);
    }
    for (int c = 0; c < 6; ++c) {
      bf16x8 kf1 = *(const bf16x8*)&Klds[16 + r][c * 32 + g * 8];
      sc1 = mfma16(qf[c], kf1, sc1);
    }

    int kj0 = kv0 + r, kj1 = kv0 + 16 + r;
    int qi0 = qbase + wave * 16 + g * 4;
    for (int i = 0; i < 4; ++i) {
      if (kj0 > qi0 + i) sc0[i] = -1e30f;
      if (kj1 > qi0 + i) sc1[i] = -1e30f;
    }

    float p0[4], p1[4];
    for (int i = 0; i < 4; ++i) {
      float tm = fmaxf(sc0[i], sc1[i]);
      for (int off = 1; off < 16; off <<= 1) tm = fmaxf(tm, __shfl_xor(tm, off, 64));
      float mnew = fmaxf(m_r[i], tm);
      float corr = exp2f((m_r[i] - mnew) * sl2);
      float e0 = exp2f((sc0[i] - mnew) * sl2);
      float e1 = exp2f((sc1[i] - mnew) * sl2);
      float rs = e0 + e1;
      for (int off = 1; off < 16; off <<= 1) rs += __shfl_xor(rs, off, 64);
      l_r[i] = l_r[i] * corr + rs;
      m_r[i] = mnew;
      for (int d = 0; d < 8; ++d) acc[d][i] *= corr;
      p0[i] = e0;
      p1[i] = e1;
    }

    for (int i = 0; i < 4; ++i) {
      Plds[wave][g * 4 + i][r] = f2bf(p0[i]);
      Plds[wave][g * 4 + i][16 + r] = f2bf(p1[i]);
    }
    // same-wave DS ops are in-order; compiler inserts lgkmcnt wait for the read
    bf16x8 pa = *(const bf16x8*)&Plds[wave][r][g * 8];
    for (int dt = 0; dt < 8; ++dt) {
      bf16x8 vf = *(const bf16x8*)&Vlds[dt * 16 + r][g * 8];
      acc[dt] = mfma16(pa, vf, acc[dt]);
    }
    __syncthreads();
  }

  for (int i = 0; i < 4; ++i) {
    float inv = 1.0f / l_r[i];
    int row = qbase + wave * 16 + g * 4 + i;
    size_t base = ((size_t)b * S + row) * 2048 + h * 128;
    for (int dt = 0; dt < 8; ++dt)
      ob[base + dt * 16 + r] = f2bf(acc[dt][i] * inv);
  }
}

// ---------- launcher ----------
extern "C" void kernel_launch(void* const* d_in, const int* in_sizes, int n_in,
                              void* d_out, int out_size, void* d_ws, size_t ws_size,
                              hipStream_t stream) {
  const float* x      = (const float*)d_in[0];
  const float* w_qkv  = (const float*)d_in[1];
  const float* b_qkv  = (const float*)d_in[2];
  const float* w_qup  = (const float*)d_in[3];
  const float* b_qup  = (const float*)d_in[4];
  const float* w_kup  = (const float*)d_in[5];
  const float* b_kup  = (const float*)d_in[6];
  const float* w_vup  = (const float*)d_in[7];
  const float* b_vup  = (const float*)d_in[8];
  const float* w_qpos = (const float*)d_in[9];
  const float* b_qpos = (const float*)d_in[10];
  const float* w_kpos = (const float*)d_in[11];
  const float* b_kpos = (const float*)d_in[12];
  const float* w_o    = (const float*)d_in[13];
  const float* b_o    = (const float*)d_in[14];
  (void)in_sizes; (void)n_in; (void)out_size; (void)ws_size;

  char* ws = (char*)d_ws;
  size_t off = 0;
  auto alloc = [&](size_t bytes) -> char* {
    char* p = ws + off;
    off += (bytes + 255) & ~(size_t)255;
    return p;
  };

  unsigned short* xb     = (unsigned short*)alloc(16777216);  // x bf16 [4096,2048]; later reused as attn out
  unsigned short* wB1    = (unsigned short*)alloc(6815744);   // [1664,2048]
  unsigned short* wB2q   = (unsigned short*)alloc(3145728);   // [3072,512]
  unsigned short* wB2k   = (unsigned short*)alloc(2097152);   // [2048,512]
  unsigned short* wB2v   = (unsigned short*)alloc(2097152);   // [2048,512]
  unsigned short* wBo    = (unsigned short*)alloc(8388608);   // [2048,2048]
  float*          bias1  = (float*)alloc(1664 * 4);
  float*          bias2q = (float*)alloc(3072 * 4);
  float*          costab = (float*)alloc(262144);
  float*          sintab = (float*)alloc(262144);
  unsigned short* latext = (unsigned short*)alloc(13631488);  // [4096,1664]
  unsigned short* tmp_q  = (unsigned short*)alloc(25165824);  // [4096,3072]
  unsigned short* tmp_k  = (unsigned short*)alloc(16777216);  // [4096,2048]
  unsigned short* tmp_v  = (unsigned short*)alloc(16777216);  // [4096,2048]
  unsigned short* qbuf   = (unsigned short*)alloc(25165824);  // [32,2048,192]
  unsigned short* kbuf   = (unsigned short*)alloc(25165824);  // [32,2048,192]
  unsigned short* vTbuf  = (unsigned short*)alloc(16777216);  // [32,128,2048]
  unsigned short* attnb  = xb;                                // alias: xb dead after GEMM1

  // 1. misc prep
  prep_misc_kernel<<<512, 256, 0, stream>>>(b_qkv, b_kpos, b_qup, b_qpos,
                                            bias1, bias2q, costab, sintab,
                                            wB1 + (size_t)1600 * 2048);
  // 2. convert x
  convx_kernel<<<8192, 256, 0, stream>>>(x, xb, 2097152);
  // 3. weight transposes (fp32 -> bf16, [K,N] -> [N,K])
  tconv_kernel<<<dim3(48, 64), 256, 0, stream>>>(w_qkv, 1536, wB1, 2048);
  tconv_kernel<<<dim3(2, 64), 256, 0, stream>>>(w_kpos, 64, wB1 + (size_t)1536 * 2048, 2048);
  tconv_kernel<<<dim3(64, 16), 256, 0, stream>>>(w_qup, 2048, wB2q, 512);
  tconv_kernel<<<dim3(32, 16), 256, 0, stream>>>(w_qpos, 1024, wB2q + (size_t)2048 * 512, 512);
  tconv_kernel<<<dim3(64, 16), 256, 0, stream>>>(w_kup, 2048, wB2k, 512);
  tconv_kernel<<<dim3(64, 16), 256, 0, stream>>>(w_vup, 2048, wB2v, 512);
  tconv_kernel<<<dim3(64, 64), 256, 0, stream>>>(w_o, 2048, wBo, 2048);

  // 4. GEMM1: lat_ext[4096,1664] = xb @ wB1^T + bias1  (includes pos_k cols 1536..1599)
  gemm_bt_kernel<0><<<dim3(13, 32), 256, 0, stream>>>(xb, 2048, wB1, 2048,
                                                      latext, 1664, bias1, 2048);
  // 5. up-projections (K=512) from latent slices
  gemm_bt_kernel<0><<<dim3(24, 32), 256, 0, stream>>>(latext, 1664, wB2q, 512,
                                                      tmp_q, 3072, bias2q, 512);
  gemm_bt_kernel<0><<<dim3(16, 32), 256, 0, stream>>>(latext + 512, 1664, wB2k, 512,
                                                      tmp_k, 2048, b_kup, 512);
  gemm_bt_kernel<0><<<dim3(16, 32), 256, 0, stream>>>(latext + 1024, 1664, wB2v, 512,
                                                      tmp_v, 2048, b_vup, 512);
  // 6. assemble q,k (RoPE) and transpose v
  assemble_qk_kernel<<<49152, 256, 0, stream>>>(tmp_q, tmp_k, latext, costab, sintab,
                                                qbuf, kbuf);
  transpose_v_kernel<<<dim3(64, 4, 32), 256, 0, stream>>>(tmp_v, vTbuf);
  // 7. causal flash attention -> attnb [4096, 2048] bf16
  flash_kernel<<<dim3(32, 16, 2), 256, 0, stream>>>(qbuf, kbuf, vTbuf, attnb);
  // 8. output projection (fp32 out + b_o)
  gemm_bt_kernel<1><<<dim3(16, 32), 256, 0, stream>>>(attnb, 2048, wBo, 2048,
                                                      d_out, 2048, b_o, 2048);
}

// Round 2
// 436.408 us; speedup vs baseline: 1.0730x; 1.0730x over previous
//
#include <hip/hip_runtime.h>
#include <cstdint>
#include <cstddef>

// ---------- types ----------
typedef __bf16 bf16x8 __attribute__((ext_vector_type(8)));
typedef float  f32x4  __attribute__((ext_vector_type(4)));
typedef unsigned short us8 __attribute__((ext_vector_type(8)));
typedef unsigned short us4 __attribute__((ext_vector_type(4)));

__device__ __forceinline__ unsigned short f2bf(float f) {
  union { float f; unsigned u; } v; v.f = f;
  unsigned r = v.u + 0x7FFFu + ((v.u >> 16) & 1u);
  return (unsigned short)(r >> 16);
}
__device__ __forceinline__ float b2f(unsigned short h) {
  union { unsigned u; float f; } v; v.u = ((unsigned)h) << 16;
  return v.f;
}
__device__ __forceinline__ f32x4 mfma16(bf16x8 a, bf16x8 b, f32x4 c) {
  return __builtin_amdgcn_mfma_f32_16x16x32_bf16(a, b, c, 0, 0, 0);
}
// async global->LDS, 16B per lane; lds dest must be wave-uniform (HW: base + lane*16)
__device__ __forceinline__ void gl_lds16(const unsigned short* g, unsigned short* l) {
  __builtin_amdgcn_global_load_lds(
      (const __attribute__((address_space(1))) void*)g,
      (__attribute__((address_space(3))) void*)l, 16, 0, 0);
}

// ---------- misc prep: bias concat, rope tables, zero-pad ----------
__global__ void prep_misc_kernel(const float* __restrict__ b_qkv,
                                 const float* __restrict__ b_kpos,
                                 const float* __restrict__ b_qup,
                                 const float* __restrict__ b_qpos,
                                 float* __restrict__ bias1,
                                 float* __restrict__ bias2q,
                                 float* __restrict__ costab,
                                 float* __restrict__ sintab,
                                 unsigned short* __restrict__ wB1pad) {
  int i = blockIdx.x * 256 + threadIdx.x;   // grid covers 131072
  if (i < 65536) {                          // 2048 x 32 rope tables
    int s = i >> 5, f = i & 31;
    float inv = powf(50000.0f, -(float)f / 32.0f);
    float a = (float)s * inv;
    costab[i] = cosf(a);
    sintab[i] = sinf(a);
  }
  if (i < 1664) bias1[i] = (i < 1536) ? b_qkv[i] : (i < 1600 ? b_kpos[i - 1536] : 0.0f);
  if (i < 3072) bias2q[i] = (i < 2048) ? b_qup[i] : b_qpos[i - 2048];
  if (i < 131072) wB1pad[i] = 0;            // rows 1600..1663 of wB1
}

// ---------- x fp32 -> bf16 ----------
__global__ void convx_kernel(const float* __restrict__ in,
                             unsigned short* __restrict__ out, int n4) {
  int i = blockIdx.x * 256 + threadIdx.x;
  if (i < n4) {
    float4 v = ((const float4*)in)[i];
    us4 o;
    o[0] = f2bf(v.x); o[1] = f2bf(v.y); o[2] = f2bf(v.z); o[3] = f2bf(v.w);
    ((us4*)out)[i] = o;
  }
}

// ---------- weight transpose + convert: out[c*ldo + r] = bf16(in[r*ldin + c]) ----------
__global__ void tconv_kernel(const float* __restrict__ in, int ldin,
                             unsigned short* __restrict__ out, int ldo) {
  __shared__ float tile[32][33];
  int c0 = blockIdx.x * 32, r0 = blockIdx.y * 32;
  int tx = threadIdx.x & 31, ty = threadIdx.x >> 5;
  for (int j = 0; j < 4; ++j)
    tile[ty + j * 8][tx] = in[(size_t)(r0 + ty + j * 8) * ldin + c0 + tx];
  __syncthreads();
  for (int j = 0; j < 4; ++j)
    out[(size_t)(c0 + ty + j * 8) * ldo + r0 + tx] = f2bf(tile[tx][ty + j * 8]);
}

// ---------- GEMM: C[M,N] = A[M,K]*Bt[N,K]^T + bias; m97 pattern: global_load_lds w16 ----------
template <int OUT_F32>
__global__ __launch_bounds__(256, 2)
void gemm_bt_kernel(const unsigned short* __restrict__ A, int lda,
                    const unsigned short* __restrict__ Bt, int ldb,
                    void* __restrict__ Cout, int ldc,
                    const float* __restrict__ bias, int K) {
  __shared__ unsigned short Alds[128 * 32];   // linear row-major [128][32]
  __shared__ unsigned short Blds[128 * 32];
  int tid = threadIdx.x;
  int wave = tid >> 6, lane = tid & 63;
  int g = lane >> 4, r = lane & 15;
  int wr = wave >> 1, wc = wave & 1;
  long brow = (long)blockIdx.y * 128, bcol = (long)blockIdx.x * 128;

  // staging: wave w covers rows [w*32, w*32+32); LDS dest wave-uniform, lane k fills base+16*k
  int srow0 = wave * 32 + (lane >> 2);
  int srow1 = srow0 + 16;
  int sseg = (lane & 3) * 8;
  const unsigned short* Ag0 = A + (brow + srow0) * (long)lda + sseg;
  const unsigned short* Ag1 = A + (brow + srow1) * (long)lda + sseg;
  const unsigned short* Bg0 = Bt + (bcol + srow0) * (long)ldb + sseg;
  const unsigned short* Bg1 = Bt + (bcol + srow1) * (long)ldb + sseg;
  unsigned short* lA0 = Alds + wave * 1024;          // shorts
  unsigned short* lA1 = Alds + wave * 1024 + 512;
  unsigned short* lB0 = Blds + wave * 1024;
  unsigned short* lB1 = Blds + wave * 1024 + 512;

  f32x4 acc[4][4];
  for (int mi = 0; mi < 4; ++mi)
    for (int ni = 0; ni < 4; ++ni)
      acc[mi][ni] = f32x4{0.f, 0.f, 0.f, 0.f};

  for (int k0 = 0; k0 < K; k0 += 32) {
    gl_lds16(Ag0 + k0, lA0);
    gl_lds16(Ag1 + k0, lA1);
    gl_lds16(Bg0 + k0, lB0);
    gl_lds16(Bg1 + k0, lB1);
    __syncthreads();   // drains vmcnt -> LDS tile ready
    bf16x8 af[4], bfv[4];
    for (int mi = 0; mi < 4; ++mi)
      af[mi] = *(const bf16x8*)&Alds[(wr * 64 + mi * 16 + r) * 32 + g * 8];
    for (int ni = 0; ni < 4; ++ni)
      bfv[ni] = *(const bf16x8*)&Blds[(wc * 64 + ni * 16 + r) * 32 + g * 8];
    __builtin_amdgcn_s_setprio(1);
    for (int mi = 0; mi < 4; ++mi)
      for (int ni = 0; ni < 4; ++ni)
        acc[mi][ni] = mfma16(af[mi], bfv[ni], acc[mi][ni]);
    __builtin_amdgcn_s_setprio(0);
    __syncthreads();   // LDS free for next tile
  }

  for (int mi = 0; mi < 4; ++mi)
    for (int ni = 0; ni < 4; ++ni) {
      long col = bcol + wc * 64 + ni * 16 + r;
      float bv = bias ? bias[col] : 0.0f;
      long rowb = brow + wr * 64 + mi * 16 + g * 4;
      for (int i = 0; i < 4; ++i) {
        float v = acc[mi][ni][i] + bv;
        if (OUT_F32)
          ((float*)Cout)[(rowb + i) * (long)ldc + col] = v;
        else
          ((unsigned short*)Cout)[(rowb + i) * (long)ldc + col] = f2bf(v);
      }
    }
}

// ---------- assemble q,k with RoPE ----------
__global__ void assemble_qk_kernel(const unsigned short* __restrict__ tmp_q,
                                   const unsigned short* __restrict__ tmp_k,
                                   const unsigned short* __restrict__ lat_ext,
                                   const float* __restrict__ costab,
                                   const float* __restrict__ sintab,
                                   unsigned short* __restrict__ qb,
                                   unsigned short* __restrict__ kb) {
  int idx = blockIdx.x * 256 + threadIdx.x;  // 32*2048*192 exact
  int d = idx % 192;
  int t = idx / 192;
  int s = t & 2047;
  int bh = t >> 11;
  int b = bh >> 4, h = bh & 15;
  size_t qo = ((size_t)bh * 2048 + s) * 192 + d;
  size_t rowA = (size_t)(b * 2048 + s);
  unsigned short qv, kv;
  if (d < 128) {
    qv = tmp_q[rowA * 3072 + h * 128 + d];
    kv = tmp_k[rowA * 2048 + h * 128 + d];
  } else {
    int dp = d - 128;
    int f = dp & 31;
    float c = costab[s * 32 + f], sn = sintab[s * 32 + f];
    int dq = (dp < 32) ? dp + 32 : dp - 32;
    float x1 = b2f(tmp_q[rowA * 3072 + 2048 + h * 64 + dp]);
    float x2 = b2f(tmp_q[rowA * 3072 + 2048 + h * 64 + dq]);
    float qr = (dp < 32) ? (x1 * c - x2 * sn) : (x1 * c + x2 * sn);
    float k1 = b2f(lat_ext[rowA * 1664 + 1536 + dp]);
    float k2 = b2f(lat_ext[rowA * 1664 + 1536 + dq]);
    float kr = (dp < 32) ? (k1 * c - k2 * sn) : (k1 * c + k2 * sn);
    qv = f2bf(qr);
    kv = f2bf(kr);
  }
  qb[qo] = qv;
  kb[qo] = kv;
}

// ---------- V transpose: tmp_v[B*S, NH*128] -> vT[B,NH,128,S] ----------
__global__ void transpose_v_kernel(const unsigned short* __restrict__ tmp_v,
                                   unsigned short* __restrict__ vT) {
  __shared__ unsigned short tile[32][33];
  int s0 = blockIdx.x * 32, d0 = blockIdx.y * 32, bh = blockIdx.z;
  int b = bh >> 4, h = bh & 15;
  int tx = threadIdx.x & 31, ty = threadIdx.x >> 5;
  const unsigned short* in = tmp_v + (size_t)b * 2048 * 2048 + h * 128;
  for (int j = 0; j < 4; ++j)
    tile[ty + j * 8][tx] = in[(size_t)(s0 + ty + j * 8) * 2048 + d0 + tx];
  __syncthreads();
  unsigned short* out = vT + (size_t)bh * 128 * 2048;
  for (int j = 0; j < 4; ++j)
    out[(size_t)(d0 + ty + j * 8) * 2048 + s0 + tx] = tile[tx][ty + j * 8];
}

// ---------- split-KV causal flash attention (partials) ----------
// 1536 blocks: bh = blockIdx.x&31, e = blockIdx.x>>5, u = 47-e (longest-first).
// u<16: qt=u (single seg). u>=16: qt=16+(u-16)/2, s=(u-16)&1; SEG=1024 KV rows (32 chunks).
// Writes unnormalized O (f32 [64][128]) + per-row (m,l) at compact slot bh*48+u.
__global__ __launch_bounds__(256, 2)
void flash_kernel(const unsigned short* __restrict__ qb,
                  const unsigned short* __restrict__ kb,
                  const unsigned short* __restrict__ vT,
                  float* __restrict__ Opart,
                  float* __restrict__ mlbuf) {
  const int S = 2048;
  int bh = blockIdx.x & 31, e = blockIdx.x >> 5;
  int u = 47 - e;
  int qt, sseg;
  if (u < 16) { qt = u; sseg = 0; }
  else { qt = 16 + ((u - 16) >> 1); sseg = (u - 16) & 1; }
  int tid = threadIdx.x, wave = tid >> 6, lane = tid & 63;
  int g = lane >> 4, r = lane & 15;
  int qbase = qt * 64;
  int cbeg = sseg * 32;
  int cend = min(cbeg + 32, 2 * (qt + 1));

  const unsigned short* qp = qb + (size_t)bh * S * 192;
  const unsigned short* kp = kb + (size_t)bh * S * 192;
  const unsigned short* vp = vT + (size_t)bh * 128 * S;

  __shared__ unsigned short Klds[32][200];
  __shared__ unsigned short Vlds[128][40];
  __shared__ unsigned short Plds[4][16][40];

  bf16x8 qf[6];
  {
    int qrow = qbase + wave * 16 + r;
    const unsigned short* qr_ = qp + (size_t)qrow * 192 + g * 8;
    for (int c = 0; c < 6; ++c) qf[c] = *(const bf16x8*)(qr_ + c * 32);
  }

  f32x4 acc[8];
  for (int d = 0; d < 8; ++d) acc[d] = f32x4{0.f, 0.f, 0.f, 0.f};
  float m_r[4], l_r[4];
  for (int i = 0; i < 4; ++i) { m_r[i] = -3.0e38f; l_r[i] = 0.f; }

  const float sl2 = 1.44269504f / 13.8564064605510183f;  // log2e / sqrt(192)

  int ks_row[3], ks_seg[3];
  for (int j = 0; j < 3; ++j) {
    int slot = j * 256 + tid;
    ks_row[j] = slot / 24;
    ks_seg[j] = slot - ks_row[j] * 24;
  }

  us8 kreg[3], vreg[2];
  {
    int kv0 = cbeg * 32;
    for (int j = 0; j < 3; ++j)
      kreg[j] = *(const us8*)(kp + (size_t)(kv0 + ks_row[j]) * 192 + ks_seg[j] * 8);
    for (int j = 0; j < 2; ++j) {
      int slot = j * 256 + tid, row = slot >> 2, seg = slot & 3;
      vreg[j] = *(const us8*)(vp + (size_t)row * S + kv0 + seg * 8);
    }
  }

  for (int ch = cbeg; ch < cend; ++ch) {
    for (int j = 0; j < 3; ++j)
      *(us8*)&Klds[ks_row[j]][ks_seg[j] * 8] = kreg[j];
    for (int j = 0; j < 2; ++j) {
      int slot = j * 256 + tid, row = slot >> 2, seg = slot & 3;
      *(us8*)&Vlds[row][seg * 8] = vreg[j];
    }
    __syncthreads();
    if (ch + 1 < cend) {
      int kv1 = (ch + 1) * 32;
      for (int j = 0; j < 3; ++j)
        kreg[j] = *(const us8*)(kp + (size_t)(kv1 + ks_row[j]) * 192 + ks_seg[j] * 8);
      for (int j = 0; j < 2; ++j) {
        int slot = j * 256 + tid, row = slot >> 2, seg = slot & 3;
        vreg[j] = *(const us8*)(vp + (size_t)row * S + kv1 + seg * 8);
      }
    }
    int kv0 = ch * 32;

    f32x4 sc0 = {0.f, 0.f, 0.f, 0.f}, sc1 = {0.f, 0.f, 0.f, 0.f};
    __builtin_amdgcn_s_setprio(1);
    for (int c = 0; c < 6; ++c) {
      bf16x8 kf0 = *(const bf16x8*)&Klds[r][c * 32 + g * 8];
      sc0 = mfma16(qf[c], kf0, sc0);
    }
    for (int c = 0; c < 6; ++c) {
      bf16x8 kf1 = *(const bf16x8*)&Klds[16 + r][c * 32 + g * 8];
      sc1 = mfma16(qf[c], kf1, sc1);
    }
    __builtin_amdgcn_s_setprio(0);

    int kj0 = kv0 + r, kj1 = kv0 + 16 + r;
    int qi0 = qbase + wave * 16 + g * 4;
    for (int i = 0; i < 4; ++i) {
      if (kj0 > qi0 + i) sc0[i] = -1e30f;
      if (kj1 > qi0 + i) sc1[i] = -1e30f;
    }

    float p0[4], p1[4];
    for (int i = 0; i < 4; ++i) {
      float tm = fmaxf(sc0[i], sc1[i]);
      for (int off = 1; off < 16; off <<= 1) tm = fmaxf(tm, __shfl_xor(tm, off, 64));
      float mnew = fmaxf(m_r[i], tm);
      float corr = exp2f((m_r[i] - mnew) * sl2);
      float e0 = exp2f((sc0[i] - mnew) * sl2);
      float e1 = exp2f((sc1[i] - mnew) * sl2);
      float rs = e0 + e1;
      for (int off = 1; off < 16; off <<= 1) rs += __shfl_xor(rs, off, 64);
      l_r[i] = l_r[i] * corr + rs;
      m_r[i] = mnew;
      for (int d = 0; d < 8; ++d) acc[d][i] *= corr;
      p0[i] = e0;
      p1[i] = e1;
    }

    for (int i = 0; i < 4; ++i) {
      Plds[wave][g * 4 + i][r] = f2bf(p0[i]);
      Plds[wave][g * 4 + i][16 + r] = f2bf(p1[i]);
    }
    bf16x8 pa = *(const bf16x8*)&Plds[wave][r][g * 8];
    __builtin_amdgcn_s_setprio(1);
    for (int dt = 0; dt < 8; ++dt) {
      bf16x8 vf = *(const bf16x8*)&Vlds[dt * 16 + r][g * 8];
      acc[dt] = mfma16(pa, vf, acc[dt]);
    }
    __builtin_amdgcn_s_setprio(0);
    __syncthreads();
  }

  // store unnormalized partial + (m,l)
  int slot = bh * 48 + u;
  float* op = Opart + (size_t)slot * 8192;
  for (int i = 0; i < 4; ++i) {
    int row = wave * 16 + g * 4 + i;
    for (int dt = 0; dt < 8; ++dt)
      op[row * 128 + dt * 16 + r] = acc[dt][i];
    if (r == 0) {
      mlbuf[(size_t)slot * 128 + row * 2]     = m_r[i];
      mlbuf[(size_t)slot * 128 + row * 2 + 1] = l_r[i];
    }
  }
}

// ---------- merge partials -> attn bf16 [B*S, 2048] ----------
__global__ void merge_kernel(const float* __restrict__ Opart,
                             const float* __restrict__ mlbuf,
                             unsigned short* __restrict__ ob) {
  int bh = blockIdx.x & 31, qt = blockIdx.x >> 5;
  int b = bh >> 4, h = bh & 15;
  int t = threadIdx.x;
  int row = t >> 2, c0 = (t & 3) * 32;
  int nseg = (qt < 16) ? 1 : 2;
  int si0 = (qt < 16) ? qt : 16 + 2 * (qt - 16);
  int slot0 = bh * 48 + si0;
  const float sl2 = 1.44269504f / 13.8564064605510183f;

  float m0 = mlbuf[(size_t)slot0 * 128 + row * 2];
  float l0 = mlbuf[(size_t)slot0 * 128 + row * 2 + 1];
  float w0 = 1.f, w1 = 0.f, L;
  if (nseg == 2) {
    float m1 = mlbuf[(size_t)(slot0 + 1) * 128 + row * 2];
    float l1 = mlbuf[(size_t)(slot0 + 1) * 128 + row * 2 + 1];
    float M = fmaxf(m0, m1);
    w0 = exp2f((m0 - M) * sl2);
    w1 = exp2f((m1 - M) * sl2);
    L = l0 * w0 + l1 * w1;
  } else {
    L = l0;
  }
  float invL = 1.f / L;
  w0 *= invL; w1 *= invL;

  const float4* p0 = (const float4*)(Opart + (size_t)slot0 * 8192 + row * 128 + c0);
  const float4* p1 = (const float4*)(Opart + (size_t)(slot0 + 1) * 8192 + row * 128 + c0);
  size_t obase = ((size_t)b * 2048 + qt * 64 + row) * 2048 + h * 128 + c0;
  for (int j = 0; j < 8; ++j) {
    float4 v = p0[j];
    float ox = v.x * w0, oy = v.y * w0, oz = v.z * w0, ow = v.w * w0;
    if (nseg == 2) {
      float4 v1 = p1[j];
      ox += v1.x * w1; oy += v1.y * w1; oz += v1.z * w1; ow += v1.w * w1;
    }
    us4 st;
    st[0] = f2bf(ox); st[1] = f2bf(oy); st[2] = f2bf(oz); st[3] = f2bf(ow);
    *(us4*)(ob + obase + j * 4) = st;
  }
}

// ---------- launcher ----------
extern "C" void kernel_launch(void* const* d_in, const int* in_sizes, int n_in,
                              void* d_out, int out_size, void* d_ws, size_t ws_size,
                              hipStream_t stream) {
  const float* x      = (const float*)d_in[0];
  const float* w_qkv  = (const float*)d_in[1];
  const float* b_qkv  = (const float*)d_in[2];
  const float* w_qup  = (const float*)d_in[3];
  const float* b_qup  = (const float*)d_in[4];
  const float* w_kup  = (const float*)d_in[5];
  const float* b_kup  = (const float*)d_in[6];
  const float* w_vup  = (const float*)d_in[7];
  const float* b_vup  = (const float*)d_in[8];
  const float* w_qpos = (const float*)d_in[9];
  const float* b_qpos = (const float*)d_in[10];
  const float* w_kpos = (const float*)d_in[11];
  const float* b_kpos = (const float*)d_in[12];
  const float* w_o    = (const float*)d_in[13];
  const float* b_o    = (const float*)d_in[14];
  (void)in_sizes; (void)n_in; (void)out_size; (void)ws_size;

  char* ws = (char*)d_ws;
  size_t off = 0;
  auto alloc = [&](size_t bytes) -> char* {
    char* p = ws + off;
    off += (bytes + 255) & ~(size_t)255;
    return p;
  };

  unsigned short* xb     = (unsigned short*)alloc(16777216);  // x bf16 [4096,2048]; reused as attn out
  unsigned short* wB1    = (unsigned short*)alloc(6815744);   // [1664,2048]
  unsigned short* wB2q   = (unsigned short*)alloc(3145728);   // [3072,512]
  unsigned short* wB2k   = (unsigned short*)alloc(2097152);   // [2048,512]
  unsigned short* wB2v   = (unsigned short*)alloc(2097152);   // [2048,512]
  unsigned short* wBo    = (unsigned short*)alloc(8388608);   // [2048,2048]
  float*          bias1  = (float*)alloc(1664 * 4);
  float*          bias2q = (float*)alloc(3072 * 4);
  float*          costab = (float*)alloc(262144);
  float*          sintab = (float*)alloc(262144);
  unsigned short* latext = (unsigned short*)alloc(13631488);  // [4096,1664]
  unsigned short* tmp_q  = (unsigned short*)alloc(25165824);  // [4096,3072]
  unsigned short* tmp_k  = (unsigned short*)alloc(16777216);  // [4096,2048]
  unsigned short* tmp_v  = (unsigned short*)alloc(16777216);  // [4096,2048]
  unsigned short* qbuf   = (unsigned short*)alloc(25165824);  // [32,2048,192]
  unsigned short* kbuf   = (unsigned short*)alloc(25165824);  // [32,2048,192]
  unsigned short* vTbuf  = (unsigned short*)alloc(16777216);  // [32,128,2048]
  unsigned short* attnb  = xb;                                // alias: xb dead after GEMM1
  // flash partials overlay the latent/tmp region (dead before flash launches):
  // need 1536*8192*4 = 50,331,648 B (Opart) + 1536*128*4 = 786,432 B (ml) <= 72.35 MB region
  float* Opart = (float*)latext;
  float* mlbuf = (float*)(((char*)latext) + 50331648);

  // 1. misc prep
  prep_misc_kernel<<<512, 256, 0, stream>>>(b_qkv, b_kpos, b_qup, b_qpos,
                                            bias1, bias2q, costab, sintab,
                                            wB1 + (size_t)1600 * 2048);
  // 2. convert x
  convx_kernel<<<8192, 256, 0, stream>>>(x, xb, 2097152);
  // 3. weight transposes (fp32 -> bf16, [K,N] -> [N,K])
  tconv_kernel<<<dim3(48, 64), 256, 0, stream>>>(w_qkv, 1536, wB1, 2048);
  tconv_kernel<<<dim3(2, 64), 256, 0, stream>>>(w_kpos, 64, wB1 + (size_t)1536 * 2048, 2048);
  tconv_kernel<<<dim3(64, 16), 256, 0, stream>>>(w_qup, 2048, wB2q, 512);
  tconv_kernel<<<dim3(32, 16), 256, 0, stream>>>(w_qpos, 1024, wB2q + (size_t)2048 * 512, 512);
  tconv_kernel<<<dim3(64, 16), 256, 0, stream>>>(w_kup, 2048, wB2k, 512);
  tconv_kernel<<<dim3(64, 16), 256, 0, stream>>>(w_vup, 2048, wB2v, 512);
  tconv_kernel<<<dim3(64, 64), 256, 0, stream>>>(w_o, 2048, wBo, 2048);

  // 4. GEMM1: lat_ext[4096,1664] = xb @ wB1^T + bias1  (includes pos_k cols 1536..1599)
  gemm_bt_kernel<0><<<dim3(13, 32), 256, 0, stream>>>(xb, 2048, wB1, 2048,
                                                      latext, 1664, bias1, 2048);
  // 5. up-projections (K=512) from latent slices
  gemm_bt_kernel<0><<<dim3(24, 32), 256, 0, stream>>>(latext, 1664, wB2q, 512,
                                                      tmp_q, 3072, bias2q, 512);
  gemm_bt_kernel<0><<<dim3(16, 32), 256, 0, stream>>>(latext + 512, 1664, wB2k, 512,
                                                      tmp_k, 2048, b_kup, 512);
  gemm_bt_kernel<0><<<dim3(16, 32), 256, 0, stream>>>(latext + 1024, 1664, wB2v, 512,
                                                      tmp_v, 2048, b_vup, 512);
  // 6. assemble q,k (RoPE) and transpose v
  assemble_qk_kernel<<<49152, 256, 0, stream>>>(tmp_q, tmp_k, latext, costab, sintab,
                                                qbuf, kbuf);
  transpose_v_kernel<<<dim3(64, 4, 32), 256, 0, stream>>>(tmp_v, vTbuf);
  // 7. split-KV causal flash attention -> partials (overlaying dead latent/tmp buffers)
  flash_kernel<<<1536, 256, 0, stream>>>(qbuf, kbuf, vTbuf, Opart, mlbuf);
  // 8. merge partials -> attnb [4096, 2048] bf16
  merge_kernel<<<1024, 256, 0, stream>>>(Opart, mlbuf, attnb);
  // 9. output projection (fp32 out + b_o)
  gemm_bt_kernel<1><<<dim3(16, 32), 256, 0, stream>>>(attnb, 2048, wBo, 2048,
                                                      d_out, 2048, b_o, 2048);
}

// Round 3
// 415.066 us; speedup vs baseline: 1.1282x; 1.0514x over previous
//
#include <hip/hip_runtime.h>
#include <cstdint>
#include <cstddef>

// ---------- types ----------
typedef __bf16 bf16x8 __attribute__((ext_vector_type(8)));
typedef float  f32x4  __attribute__((ext_vector_type(4)));
typedef unsigned short us8 __attribute__((ext_vector_type(8)));
typedef unsigned short us4 __attribute__((ext_vector_type(4)));

__device__ __forceinline__ unsigned short f2bf(float f) {
  union { float f; unsigned u; } v; v.f = f;
  unsigned r = v.u + 0x7FFFu + ((v.u >> 16) & 1u);
  return (unsigned short)(r >> 16);
}
__device__ __forceinline__ float b2f(unsigned short h) {
  union { unsigned u; float f; } v; v.u = ((unsigned)h) << 16;
  return v.f;
}
__device__ __forceinline__ f32x4 mfma16(bf16x8 a, bf16x8 b, f32x4 c) {
  return __builtin_amdgcn_mfma_f32_16x16x32_bf16(a, b, c, 0, 0, 0);
}
// async global->LDS, 16B per lane; lds dest wave-uniform (HW writes base + lane*16)
__device__ __forceinline__ void gl_lds16(const unsigned short* g, unsigned short* l) {
  __builtin_amdgcn_global_load_lds(
      (const __attribute__((address_space(1))) void*)g,
      (__attribute__((address_space(3))) void*)l, 16, 0, 0);
}

// ---------- flash schedule: 63 segments/bh of <=22 KV-chunks, sorted longest-first ----------
__device__ const signed char d_seg_qt[63] = {
  10,11,12,13,14,15,16,17,18,19,20,21,21,22,22,23,23,24,24,25,25,26,26,27,27,28,28,29,29,30,30,31,31,
   9,20,31,  8,19,30,  7,18,29,  6,17,28,  5,16,27,  4,15,26,  3,14,25,  2,13,24,  1,12,23,  0,11,22};
__device__ const signed char d_seg_ss[63] = {
   0, 0, 0, 0, 0, 0, 0, 0, 0, 0, 0, 0, 1, 0, 1, 0, 1, 0, 1, 0, 1, 0, 1, 0, 1, 0, 1, 0, 1, 0, 1, 0, 1,
   0, 1, 2,  0, 1, 2,  0, 1, 2,  0, 1, 2,  0, 1, 2,  0, 1, 2,  0, 1, 2,  0, 1, 2,  0, 1, 2,  0, 1, 2};
__device__ const signed char d_rev[32][3] = {
  {60,-1,-1},{57,-1,-1},{54,-1,-1},{51,-1,-1},{48,-1,-1},{45,-1,-1},{42,-1,-1},{39,-1,-1},
  {36,-1,-1},{33,-1,-1},{ 0,-1,-1},{ 1,61,-1},{ 2,58,-1},{ 3,55,-1},{ 4,52,-1},{ 5,49,-1},
  { 6,46,-1},{ 7,43,-1},{ 8,40,-1},{ 9,37,-1},{10,34,-1},{11,12,-1},{13,14,62},{15,16,59},
  {17,18,56},{19,20,53},{21,22,50},{23,24,47},{25,26,44},{27,28,41},{29,30,38},{31,32,35}};

// ---------- misc prep: bias concat, rope tables, zero-pad ----------
__global__ void prep_misc_kernel(const float* __restrict__ b_qkv,
                                 const float* __restrict__ b_kpos,
                                 const float* __restrict__ b_qup,
                                 const float* __restrict__ b_qpos,
                                 float* __restrict__ bias1,
                                 float* __restrict__ bias2q,
                                 float* __restrict__ costab,
                                 float* __restrict__ sintab,
                                 unsigned short* __restrict__ wB1pad) {
  int i = blockIdx.x * 256 + threadIdx.x;   // grid covers 131072
  if (i < 65536) {                          // 2048 x 32 rope tables
    int s = i >> 5, f = i & 31;
    float inv = powf(50000.0f, -(float)f / 32.0f);
    float a = (float)s * inv;
    costab[i] = cosf(a);
    sintab[i] = sinf(a);
  }
  if (i < 1664) bias1[i] = (i < 1536) ? b_qkv[i] : (i < 1600 ? b_kpos[i - 1536] : 0.0f);
  if (i < 3072) bias2q[i] = (i < 2048) ? b_qup[i] : b_qpos[i - 2048];
  if (i < 131072) wB1pad[i] = 0;            // rows 1600..1663 of wB1
}

// ---------- x fp32 -> bf16 ----------
__global__ void convx_kernel(const float* __restrict__ in,
                             unsigned short* __restrict__ out, int n4) {
  int i = blockIdx.x * 256 + threadIdx.x;
  if (i < n4) {
    float4 v = ((const float4*)in)[i];
    us4 o;
    o[0] = f2bf(v.x); o[1] = f2bf(v.y); o[2] = f2bf(v.z); o[3] = f2bf(v.w);
    ((us4*)out)[i] = o;
  }
}

// ---------- weight transpose + convert: out[c*ldo + r] = bf16(in[r*ldin + c]) ----------
__global__ void tconv_kernel(const float* __restrict__ in, int ldin,
                             unsigned short* __restrict__ out, int ldo) {
  __shared__ float tile[32][33];
  int c0 = blockIdx.x * 32, r0 = blockIdx.y * 32;
  int tx = threadIdx.x & 31, ty = threadIdx.x >> 5;
  for (int j = 0; j < 4; ++j)
    tile[ty + j * 8][tx] = in[(size_t)(r0 + ty + j * 8) * ldin + c0 + tx];
  __syncthreads();
  for (int j = 0; j < 4; ++j)
    out[(size_t)(c0 + ty + j * 8) * ldo + r0 + tx] = f2bf(tile[tx][ty + j * 8]);
}

// ---------- GEMM: C[M,N] = A[M,K]*Bt[N,K]^T + bias ----------
// 128x128 tile, BK=64, global_load_lds w16 with pre-swizzled source, swizzled ds_read.
template <int OUT_F32>
__global__ __launch_bounds__(256, 2)
void gemm_bt_kernel(const unsigned short* __restrict__ A, int lda,
                    const unsigned short* __restrict__ Bt, int ldb,
                    void* __restrict__ Cout, int ldc,
                    const float* __restrict__ bias, int K) {
  __shared__ unsigned short Alds[128 * 64];   // [row][64] shorts, 16B-block-swizzled
  __shared__ unsigned short Blds[128 * 64];
  int tid = threadIdx.x;
  int wave = tid >> 6, lane = tid & 63;
  int g = lane >> 4, r = lane & 15;
  int wr = wave >> 1, wc = wave & 1;
  long brow = (long)blockIdx.y * 128, bcol = (long)blockIdx.x * 128;

  // staging: wave w stages rows [w*32, w*32+32); call c covers 8 rows.
  // LDS is linear (dest = base + lane*16); swizzle done on the GLOBAL source col:
  // LDS 16B-block b of row holds global col-block b ^ (row&7).
  int srowl = lane >> 3;                        // 0..7 within the 8-row call
  int sw = ((lane & 7) ^ (srowl & 7)) * 8;      // swizzled col offset (shorts)
  const unsigned short* Abase = A + (brow + wave * 32 + srowl) * (long)lda + sw;
  const unsigned short* Bbase = Bt + (bcol + wave * 32 + srowl) * (long)ldb + sw;

  f32x4 acc[4][4];
  for (int mi = 0; mi < 4; ++mi)
    for (int ni = 0; ni < 4; ++ni)
      acc[mi][ni] = f32x4{0.f, 0.f, 0.f, 0.f};

  const char* Ab = (const char*)Alds;
  const char* Bb = (const char*)Blds;
  int rx = (r & 7) << 4;

  for (int k0 = 0; k0 < K; k0 += 64) {
    for (int c = 0; c < 4; ++c) {
      gl_lds16(Abase + (size_t)c * 8 * lda + k0, Alds + (wave * 32 + c * 8) * 64);
      gl_lds16(Bbase + (size_t)c * 8 * ldb + k0, Blds + (wave * 32 + c * 8) * 64);
    }
    __syncthreads();   // drains vmcnt -> LDS tile ready
    for (int kk = 0; kk < 2; ++kk) {
      bf16x8 af[4], bfv[4];
      for (int mi = 0; mi < 4; ++mi)
        af[mi] = *(const bf16x8*)(Ab + (size_t)(wr * 64 + mi * 16 + r) * 128 +
                                  ((kk * 64 + g * 16) ^ rx));
      for (int ni = 0; ni < 4; ++ni)
        bfv[ni] = *(const bf16x8*)(Bb + (size_t)(wc * 64 + ni * 16 + r) * 128 +
                                   ((kk * 64 + g * 16) ^ rx));
      __builtin_amdgcn_s_setprio(1);
      for (int mi = 0; mi < 4; ++mi)
        for (int ni = 0; ni < 4; ++ni)
          acc[mi][ni] = mfma16(af[mi], bfv[ni], acc[mi][ni]);
      __builtin_amdgcn_s_setprio(0);
    }
    __syncthreads();   // LDS free for next tile
  }

  for (int mi = 0; mi < 4; ++mi)
    for (int ni = 0; ni < 4; ++ni) {
      long col = bcol + wc * 64 + ni * 16 + r;
      float bv = bias ? bias[col] : 0.0f;
      long rowb = brow + wr * 64 + mi * 16 + g * 4;
      for (int i = 0; i < 4; ++i) {
        float v = acc[mi][ni][i] + bv;
        if (OUT_F32)
          ((float*)Cout)[(rowb + i) * (long)ldc + col] = v;
        else
          ((unsigned short*)Cout)[(rowb + i) * (long)ldc + col] = f2bf(v);
      }
    }
}

// ---------- assemble q,k with RoPE ----------
__global__ void assemble_qk_kernel(const unsigned short* __restrict__ tmp_q,
                                   const unsigned short* __restrict__ tmp_k,
                                   const unsigned short* __restrict__ lat_ext,
                                   const float* __restrict__ costab,
                                   const float* __restrict__ sintab,
                                   unsigned short* __restrict__ qb,
                                   unsigned short* __restrict__ kb) {
  int idx = blockIdx.x * 256 + threadIdx.x;  // 32*2048*192 exact
  int d = idx % 192;
  int t = idx / 192;
  int s = t & 2047;
  int bh = t >> 11;
  int b = bh >> 4, h = bh & 15;
  size_t qo = ((size_t)bh * 2048 + s) * 192 + d;
  size_t rowA = (size_t)(b * 2048 + s);
  unsigned short qv, kv;
  if (d < 128) {
    qv = tmp_q[rowA * 3072 + h * 128 + d];
    kv = tmp_k[rowA * 2048 + h * 128 + d];
  } else {
    int dp = d - 128;
    int f = dp & 31;
    float c = costab[s * 32 + f], sn = sintab[s * 32 + f];
    int dq = (dp < 32) ? dp + 32 : dp - 32;
    float x1 = b2f(tmp_q[rowA * 3072 + 2048 + h * 64 + dp]);
    float x2 = b2f(tmp_q[rowA * 3072 + 2048 + h * 64 + dq]);
    float qr = (dp < 32) ? (x1 * c - x2 * sn) : (x1 * c + x2 * sn);
    float k1 = b2f(lat_ext[rowA * 1664 + 1536 + dp]);
    float k2 = b2f(lat_ext[rowA * 1664 + 1536 + dq]);
    float kr = (dp < 32) ? (k1 * c - k2 * sn) : (k1 * c + k2 * sn);
    qv = f2bf(qr);
    kv = f2bf(kr);
  }
  qb[qo] = qv;
  kb[qo] = kv;
}

// ---------- V transpose: tmp_v[B*S, NH*128] -> vT[B,NH,128,S] ----------
__global__ void transpose_v_kernel(const unsigned short* __restrict__ tmp_v,
                                   unsigned short* __restrict__ vT) {
  __shared__ unsigned short tile[32][33];
  int s0 = blockIdx.x * 32, d0 = blockIdx.y * 32, bh = blockIdx.z;
  int b = bh >> 4, h = bh & 15;
  int tx = threadIdx.x & 31, ty = threadIdx.x >> 5;
  const unsigned short* in = tmp_v + (size_t)b * 2048 * 2048 + h * 128;
  for (int j = 0; j < 4; ++j)
    tile[ty + j * 8][tx] = in[(size_t)(s0 + ty + j * 8) * 2048 + d0 + tx];
  __syncthreads();
  unsigned short* out = vT + (size_t)bh * 128 * 2048;
  for (int j = 0; j < 4; ++j)
    out[(size_t)(d0 + ty + j * 8) * 2048 + s0 + tx] = tile[tx][ty + j * 8];
}

// ---------- split-KV causal flash attention (partials) ----------
// 2016 blocks: bh = blockIdx.x&31, e = blockIdx.x>>5 (schedule table, longest-first).
// Segment = up to 22 KV-chunks of 32 rows. Unnormalized O (f32 [64][128]) + (m,l)
// stored at slot bh*63+e. K/V LDS are XOR-swizzled (T2) to kill bank conflicts.
__global__ __launch_bounds__(256, 2)
void flash_kernel(const unsigned short* __restrict__ qb,
                  const unsigned short* __restrict__ kb,
                  const unsigned short* __restrict__ vT,
                  float* __restrict__ Opart,
                  float* __restrict__ mlbuf) {
  const int S = 2048;
  int bh = blockIdx.x & 31, e = blockIdx.x >> 5;
  int qt = d_seg_qt[e], sseg = d_seg_ss[e];
  int tid = threadIdx.x, wave = tid >> 6, lane = tid & 63;
  int g = lane >> 4, r = lane & 15;
  int qbase = qt * 64;
  int cbeg = sseg * 22;
  int cend = min(cbeg + 22, 2 * (qt + 1));

  const unsigned short* qp = qb + (size_t)bh * S * 192;
  const unsigned short* kp = kb + (size_t)bh * S * 192;
  const unsigned short* vp = vT + (size_t)bh * 128 * S;

  __shared__ unsigned short Klds[32 * 192];   // swizzled: blk16 ^= row&7
  __shared__ unsigned short Vlds[128 * 32];   // swizzled: blk16 ^= row&3
  __shared__ unsigned short Plds[4][16][40];
  char* Kb = (char*)Klds;
  char* Vb = (char*)Vlds;

  bf16x8 qf[6];
  {
    int qrow = qbase + wave * 16 + r;
    const unsigned short* qr_ = qp + (size_t)qrow * 192 + g * 8;
    for (int c = 0; c < 6; ++c) qf[c] = *(const bf16x8*)(qr_ + c * 32);
  }

  f32x4 acc[8];
  for (int d = 0; d < 8; ++d) acc[d] = f32x4{0.f, 0.f, 0.f, 0.f};
  float m_r[4], l_r[4];
  for (int i = 0; i < 4; ++i) { m_r[i] = -3.0e38f; l_r[i] = 0.f; }

  const float sl2 = 1.44269504f / 13.8564064605510183f;  // log2e / sqrt(192)

  int ks_row[3], ks_seg[3];
  for (int j = 0; j < 3; ++j) {
    int slot = j * 256 + tid;
    ks_row[j] = slot / 24;
    ks_seg[j] = slot - ks_row[j] * 24;
  }
  int rx7 = (r & 7) << 4, rx3 = (r & 3) << 4;

  us8 kreg[3], vreg[2];
  {
    int kv0 = cbeg * 32;
    for (int j = 0; j < 3; ++j)
      kreg[j] = *(const us8*)(kp + (size_t)(kv0 + ks_row[j]) * 192 + ks_seg[j] * 8);
    for (int j = 0; j < 2; ++j) {
      int slot = j * 256 + tid, row = slot >> 2, seg = slot & 3;
      vreg[j] = *(const us8*)(vp + (size_t)row * S + kv0 + seg * 8);
    }
  }

  for (int ch = cbeg; ch < cend; ++ch) {
    for (int j = 0; j < 3; ++j)
      *(us8*)(Kb + (size_t)ks_row[j] * 384 +
              ((ks_seg[j] * 16) ^ ((ks_row[j] & 7) << 4))) = kreg[j];
    for (int j = 0; j < 2; ++j) {
      int slot = j * 256 + tid, row = slot >> 2, seg = slot & 3;
      *(us8*)(Vb + (size_t)row * 64 + ((seg * 16) ^ ((row & 3) << 4))) = vreg[j];
    }
    __syncthreads();
    if (ch + 1 < cend) {
      int kv1 = (ch + 1) * 32;
      for (int j = 0; j < 3; ++j)
        kreg[j] = *(const us8*)(kp + (size_t)(kv1 + ks_row[j]) * 192 + ks_seg[j] * 8);
      for (int j = 0; j < 2; ++j) {
        int slot = j * 256 + tid, row = slot >> 2, seg = slot & 3;
        vreg[j] = *(const us8*)(vp + (size_t)row * S + kv1 + seg * 8);
      }
    }
    int kv0 = ch * 32;

    f32x4 sc0 = {0.f, 0.f, 0.f, 0.f}, sc1 = {0.f, 0.f, 0.f, 0.f};
    __builtin_amdgcn_s_setprio(1);
    for (int c = 0; c < 6; ++c) {
      bf16x8 kf0 = *(const bf16x8*)(Kb + (size_t)r * 384 + (((c * 4 + g) * 16) ^ rx7));
      sc0 = mfma16(qf[c], kf0, sc0);
    }
    for (int c = 0; c < 6; ++c) {
      bf16x8 kf1 = *(const bf16x8*)(Kb + (size_t)(16 + r) * 384 + (((c * 4 + g) * 16) ^ rx7));
      sc1 = mfma16(qf[c], kf1, sc1);
    }
    __builtin_amdgcn_s_setprio(0);

    int kj0 = kv0 + r, kj1 = kv0 + 16 + r;
    int qi0 = qbase + wave * 16 + g * 4;
    for (int i = 0; i < 4; ++i) {
      if (kj0 > qi0 + i) sc0[i] = -1e30f;
      if (kj1 > qi0 + i) sc1[i] = -1e30f;
    }

    float p0[4], p1[4];
    for (int i = 0; i < 4; ++i) {
      float tm = fmaxf(sc0[i], sc1[i]);
      for (int off = 1; off < 16; off <<= 1) tm = fmaxf(tm, __shfl_xor(tm, off, 64));
      float mnew = fmaxf(m_r[i], tm);
      float corr = exp2f((m_r[i] - mnew) * sl2);
      float e0 = exp2f((sc0[i] - mnew) * sl2);
      float e1 = exp2f((sc1[i] - mnew) * sl2);
      float rs = e0 + e1;
      for (int off = 1; off < 16; off <<= 1) rs += __shfl_xor(rs, off, 64);
      l_r[i] = l_r[i] * corr + rs;
      m_r[i] = mnew;
      for (int d = 0; d < 8; ++d) acc[d][i] *= corr;
      p0[i] = e0;
      p1[i] = e1;
    }

    for (int i = 0; i < 4; ++i) {
      Plds[wave][g * 4 + i][r] = f2bf(p0[i]);
      Plds[wave][g * 4 + i][16 + r] = f2bf(p1[i]);
    }
    bf16x8 pa = *(const bf16x8*)&Plds[wave][r][g * 8];
    __builtin_amdgcn_s_setprio(1);
    for (int dt = 0; dt < 8; ++dt) {
      bf16x8 vf = *(const bf16x8*)(Vb + (size_t)(dt * 16 + r) * 64 + ((g * 16) ^ rx3));
      acc[dt] = mfma16(pa, vf, acc[dt]);
    }
    __builtin_amdgcn_s_setprio(0);
    __syncthreads();
  }

  // store unnormalized partial + (m,l)
  size_t slot = (size_t)bh * 63 + e;
  float* op = Opart + slot * 8192;
  for (int i = 0; i < 4; ++i) {
    int row = wave * 16 + g * 4 + i;
    for (int dt = 0; dt < 8; ++dt)
      op[row * 128 + dt * 16 + r] = acc[dt][i];
    if (r == 0) {
      mlbuf[slot * 128 + row * 2]     = m_r[i];
      mlbuf[slot * 128 + row * 2 + 1] = l_r[i];
    }
  }
}

// ---------- merge partials -> attn bf16 [B*S, 2048] ----------
__global__ void merge_kernel(const float* __restrict__ Opart,
                             const float* __restrict__ mlbuf,
                             unsigned short* __restrict__ ob) {
  int qt = blockIdx.x >> 5, bh = blockIdx.x & 31;
  int b = bh >> 4, h = bh & 15;
  int t = threadIdx.x;
  int row = t >> 2, c0 = (t & 3) * 32;
  const float sl2 = 1.44269504f / 13.8564064605510183f;
  int ns = (qt <= 10) ? 1 : (qt <= 21 ? 2 : 3);

  size_t slot[3];
  float m[3], l[3], w[3];
  float M = -3.0e38f;
#pragma unroll
  for (int j = 0; j < 3; ++j) {
    if (j < ns) {
      slot[j] = (size_t)bh * 63 + d_rev[qt][j];
      m[j] = mlbuf[slot[j] * 128 + row * 2];
      l[j] = mlbuf[slot[j] * 128 + row * 2 + 1];
      M = fmaxf(M, m[j]);
    }
  }
  float L = 0.f;
#pragma unroll
  for (int j = 0; j < 3; ++j) {
    if (j < ns) { w[j] = exp2f((m[j] - M) * sl2); L += w[j] * l[j]; }
  }
  float invL = 1.f / L;
#pragma unroll
  for (int j = 0; j < 3; ++j) if (j < ns) w[j] *= invL;

  size_t obase = ((size_t)b * 2048 + qt * 64 + row) * 2048 + h * 128 + c0;
  for (int blk = 0; blk < 8; ++blk) {
    float ox = 0.f, oy = 0.f, oz = 0.f, ow = 0.f;
#pragma unroll
    for (int j = 0; j < 3; ++j) {
      if (j < ns) {
        float4 v = *(const float4*)(Opart + slot[j] * 8192 + row * 128 + c0 + blk * 4);
        ox += v.x * w[j]; oy += v.y * w[j]; oz += v.z * w[j]; ow += v.w * w[j];
      }
    }
    us4 st;
    st[0] = f2bf(ox); st[1] = f2bf(oy); st[2] = f2bf(oz); st[3] = f2bf(ow);
    *(us4*)(ob + obase + blk * 4) = st;
  }
}

// ---------- launcher ----------
extern "C" void kernel_launch(void* const* d_in, const int* in_sizes, int n_in,
                              void* d_out, int out_size, void* d_ws, size_t ws_size,
                              hipStream_t stream) {
  const float* x      = (const float*)d_in[0];
  const float* w_qkv  = (const float*)d_in[1];
  const float* b_qkv  = (const float*)d_in[2];
  const float* w_qup  = (const float*)d_in[3];
  const float* b_qup  = (const float*)d_in[4];
  const float* w_kup  = (const float*)d_in[5];
  const float* b_kup  = (const float*)d_in[6];
  const float* w_vup  = (const float*)d_in[7];
  const float* b_vup  = (const float*)d_in[8];
  const float* w_qpos = (const float*)d_in[9];
  const float* b_qpos = (const float*)d_in[10];
  const float* w_kpos = (const float*)d_in[11];
  const float* b_kpos = (const float*)d_in[12];
  const float* w_o    = (const float*)d_in[13];
  const float* b_o    = (const float*)d_in[14];
  (void)in_sizes; (void)n_in; (void)out_size; (void)ws_size;

  char* ws = (char*)d_ws;
  size_t off = 0;
  auto alloc = [&](size_t bytes) -> char* {
    char* p = ws + off;
    off += (bytes + 255) & ~(size_t)255;
    return p;
  };

  unsigned short* xb     = (unsigned short*)alloc(16777216);  // x bf16 [4096,2048]; reused as attn out
  unsigned short* wB1    = (unsigned short*)alloc(6815744);   // [1664,2048]
  unsigned short* wB2q   = (unsigned short*)alloc(3145728);   // [3072,512]
  unsigned short* wB2k   = (unsigned short*)alloc(2097152);   // [2048,512]
  unsigned short* wB2v   = (unsigned short*)alloc(2097152);   // [2048,512]
  unsigned short* wBo    = (unsigned short*)alloc(8388608);   // [2048,2048]
  float*          bias1  = (float*)alloc(1664 * 4);
  float*          bias2q = (float*)alloc(3072 * 4);
  float*          costab = (float*)alloc(262144);
  float*          sintab = (float*)alloc(262144);
  unsigned short* latext = (unsigned short*)alloc(13631488);  // [4096,1664]
  unsigned short* tmp_q  = (unsigned short*)alloc(25165824);  // [4096,3072]
  unsigned short* tmp_k  = (unsigned short*)alloc(16777216);  // [4096,2048]
  unsigned short* tmp_v  = (unsigned short*)alloc(16777216);  // [4096,2048]
  unsigned short* qbuf   = (unsigned short*)alloc(25165824);  // [32,2048,192]
  unsigned short* kbuf   = (unsigned short*)alloc(25165824);  // [32,2048,192]
  unsigned short* vTbuf  = (unsigned short*)alloc(16777216);  // [32,128,2048]
  unsigned short* attnb  = xb;                                // alias: xb dead after GEMM1
  // flash partials overlay the dead latent/tmp region (72,351,744 B):
  // Opart 2016*8192*4 = 66,060,288 B; ml 2016*128*4 = 1,032,192 B -> 67.1 MB, fits.
  float* Opart = (float*)latext;
  float* mlbuf = (float*)(((char*)latext) + 66060288);

  // 1. misc prep
  prep_misc_kernel<<<512, 256, 0, stream>>>(b_qkv, b_kpos, b_qup, b_qpos,
                                            bias1, bias2q, costab, sintab,
                                            wB1 + (size_t)1600 * 2048);
  // 2. convert x
  convx_kernel<<<8192, 256, 0, stream>>>(x, xb, 2097152);
  // 3. weight transposes (fp32 -> bf16, [K,N] -> [N,K])
  tconv_kernel<<<dim3(48, 64), 256, 0, stream>>>(w_qkv, 1536, wB1, 2048);
  tconv_kernel<<<dim3(2, 64), 256, 0, stream>>>(w_kpos, 64, wB1 + (size_t)1536 * 2048, 2048);
  tconv_kernel<<<dim3(64, 16), 256, 0, stream>>>(w_qup, 2048, wB2q, 512);
  tconv_kernel<<<dim3(32, 16), 256, 0, stream>>>(w_qpos, 1024, wB2q + (size_t)2048 * 512, 512);
  tconv_kernel<<<dim3(64, 16), 256, 0, stream>>>(w_kup, 2048, wB2k, 512);
  tconv_kernel<<<dim3(64, 16), 256, 0, stream>>>(w_vup, 2048, wB2v, 512);
  tconv_kernel<<<dim3(64, 64), 256, 0, stream>>>(w_o, 2048, wBo, 2048);

  // 4. GEMM1: lat_ext[4096,1664] = xb @ wB1^T + bias1  (includes pos_k cols 1536..1599)
  gemm_bt_kernel<0><<<dim3(13, 32), 256, 0, stream>>>(xb, 2048, wB1, 2048,
                                                      latext, 1664, bias1, 2048);
  // 5. up-projections (K=512) from latent slices
  gemm_bt_kernel<0><<<dim3(24, 32), 256, 0, stream>>>(latext, 1664, wB2q, 512,
                                                      tmp_q, 3072, bias2q, 512);
  gemm_bt_kernel<0><<<dim3(16, 32), 256, 0, stream>>>(latext + 512, 1664, wB2k, 512,
                                                      tmp_k, 2048, b_kup, 512);
  gemm_bt_kernel<0><<<dim3(16, 32), 256, 0, stream>>>(latext + 1024, 1664, wB2v, 512,
                                                      tmp_v, 2048, b_vup, 512);
  // 6. assemble q,k (RoPE) and transpose v
  assemble_qk_kernel<<<49152, 256, 0, stream>>>(tmp_q, tmp_k, latext, costab, sintab,
                                                qbuf, kbuf);
  transpose_v_kernel<<<dim3(64, 4, 32), 256, 0, stream>>>(tmp_v, vTbuf);
  // 7. split-KV causal flash attention -> partials (overlaying dead latent/tmp buffers)
  flash_kernel<<<2016, 256, 0, stream>>>(qbuf, kbuf, vTbuf, Opart, mlbuf);
  // 8. merge partials -> attnb [4096, 2048] bf16
  merge_kernel<<<1024, 256, 0, stream>>>(Opart, mlbuf, attnb);
  // 9. output projection (fp32 out + b_o)
  gemm_bt_kernel<1><<<dim3(16, 32), 256, 0, stream>>>(attnb, 2048, wBo, 2048,
                                                      d_out, 2048, b_o, 2048);
}

// Round 4
// 301.918 us; speedup vs baseline: 1.5510x; 1.3748x over previous
//
#include <hip/hip_runtime.h>
#include <cstdint>
#include <cstddef>

// ---------- types ----------
typedef __bf16 bf16x8 __attribute__((ext_vector_type(8)));
typedef float  f32x4  __attribute__((ext_vector_type(4)));
typedef unsigned short us8 __attribute__((ext_vector_type(8)));
typedef unsigned short us4 __attribute__((ext_vector_type(4)));

__device__ __forceinline__ unsigned short f2bf(float f) {
  union { float f; unsigned u; } v; v.f = f;
  unsigned r = v.u + 0x7FFFu + ((v.u >> 16) & 1u);
  return (unsigned short)(r >> 16);
}
__device__ __forceinline__ float b2f(unsigned short h) {
  union { unsigned u; float f; } v; v.u = ((unsigned)h) << 16;
  return v.f;
}
__device__ __forceinline__ f32x4 mfma16(bf16x8 a, bf16x8 b, f32x4 c) {
  return __builtin_amdgcn_mfma_f32_16x16x32_bf16(a, b, c, 0, 0, 0);
}
// async global->LDS, 16B per lane; lds dest wave-uniform (HW writes base + lane*16)
__device__ __forceinline__ void gl_lds16(const unsigned short* g, unsigned short* l) {
  __builtin_amdgcn_global_load_lds(
      (const __attribute__((address_space(1))) void*)g,
      (__attribute__((address_space(3))) void*)l, 16, 0, 0);
}

// ---------- misc prep: bias concat, rope tables, zero-pad ----------
__global__ void prep_misc_kernel(const float* __restrict__ b_qkv,
                                 const float* __restrict__ b_kpos,
                                 const float* __restrict__ b_qup,
                                 const float* __restrict__ b_qpos,
                                 float* __restrict__ bias1,
                                 float* __restrict__ bias2q,
                                 float* __restrict__ costab,
                                 float* __restrict__ sintab,
                                 unsigned short* __restrict__ wB1pad) {
  int i = blockIdx.x * 256 + threadIdx.x;   // grid covers 131072
  if (i < 65536) {                          // 2048 x 32 rope tables
    int s = i >> 5, f = i & 31;
    float inv = powf(50000.0f, -(float)f / 32.0f);
    float a = (float)s * inv;
    costab[i] = cosf(a);
    sintab[i] = sinf(a);
  }
  if (i < 1664) bias1[i] = (i < 1536) ? b_qkv[i] : (i < 1600 ? b_kpos[i - 1536] : 0.0f);
  if (i < 3072) bias2q[i] = (i < 2048) ? b_qup[i] : b_qpos[i - 2048];
  if (i < 131072) wB1pad[i] = 0;            // rows 1600..1663 of wB1
}

// ---------- x fp32 -> bf16 ----------
__global__ void convx_kernel(const float* __restrict__ in,
                             unsigned short* __restrict__ out, int n4) {
  int i = blockIdx.x * 256 + threadIdx.x;
  if (i < n4) {
    float4 v = ((const float4*)in)[i];
    us4 o;
    o[0] = f2bf(v.x); o[1] = f2bf(v.y); o[2] = f2bf(v.z); o[3] = f2bf(v.w);
    ((us4*)out)[i] = o;
  }
}

// ---------- weight transpose + convert: out[c*ldo + r] = bf16(in[r*ldin + c]) ----------
__global__ void tconv_kernel(const float* __restrict__ in, int ldin,
                             unsigned short* __restrict__ out, int ldo) {
  __shared__ float tile[32][33];
  int c0 = blockIdx.x * 32, r0 = blockIdx.y * 32;
  int tx = threadIdx.x & 31, ty = threadIdx.x >> 5;
  for (int j = 0; j < 4; ++j)
    tile[ty + j * 8][tx] = in[(size_t)(r0 + ty + j * 8) * ldin + c0 + tx];
  __syncthreads();
  for (int j = 0; j < 4; ++j)
    out[(size_t)(c0 + ty + j * 8) * ldo + r0 + tx] = f2bf(tile[tx][ty + j * 8]);
}

// ---------- GEMM: C[M,N] = A[M,K]*Bt[N,K]^T + bias ----------
// OUT_MODE: 0 = bf16 row-major, 1 = f32 row-major, 2 = bf16 transposed (vT epilogue).
// 128x128 tile, BK=64, global_load_lds w16 with pre-swizzled source, swizzled ds_read.
template <int OUT_MODE>
__global__ __launch_bounds__(256, 2)
void gemm_bt_kernel(const unsigned short* __restrict__ A, int lda,
                    const unsigned short* __restrict__ Bt, int ldb,
                    void* __restrict__ Cout, int ldc,
                    const float* __restrict__ bias, int K) {
  __shared__ unsigned short smem[OUT_MODE == 2 ? 128 * 136 : 128 * 128];
  unsigned short* Alds = smem;               // [128][64] shorts, 16B-block-swizzled
  unsigned short* Blds = smem + 128 * 64;
  int tid = threadIdx.x;
  int wave = tid >> 6, lane = tid & 63;
  int g = lane >> 4, r = lane & 15;
  int wr = wave >> 1, wc = wave & 1;
  long brow = (long)blockIdx.y * 128, bcol = (long)blockIdx.x * 128;

  // staging: wave w stages rows [w*32, w*32+32); each gl_lds call covers 8 rows.
  // LDS linear dest; swizzle on the GLOBAL source col: blk16 b of row holds b ^ (row&7).
  int srowl = lane >> 3;                        // 0..7 within the 8-row call
  int sw = ((lane & 7) ^ (srowl & 7)) * 8;      // swizzled col offset (shorts)
  const unsigned short* Abase = A + (brow + wave * 32 + srowl) * (long)lda + sw;
  const unsigned short* Bbase = Bt + (bcol + wave * 32 + srowl) * (long)ldb + sw;

  f32x4 acc[4][4];
  for (int mi = 0; mi < 4; ++mi)
    for (int ni = 0; ni < 4; ++ni)
      acc[mi][ni] = f32x4{0.f, 0.f, 0.f, 0.f};

  const char* Ab = (const char*)Alds;
  const char* Bb = (const char*)Blds;
  int rx = (r & 7) << 4;

  for (int k0 = 0; k0 < K; k0 += 64) {
    for (int c = 0; c < 4; ++c) {
      gl_lds16(Abase + (size_t)c * 8 * lda + k0, Alds + (wave * 32 + c * 8) * 64);
      gl_lds16(Bbase + (size_t)c * 8 * ldb + k0, Blds + (wave * 32 + c * 8) * 64);
    }
    __syncthreads();   // drains vmcnt -> LDS tile ready
    for (int kk = 0; kk < 2; ++kk) {
      bf16x8 af[4], bfv[4];
      for (int mi = 0; mi < 4; ++mi)
        af[mi] = *(const bf16x8*)(Ab + (size_t)(wr * 64 + mi * 16 + r) * 128 +
                                  ((kk * 64 + g * 16) ^ rx));
      for (int ni = 0; ni < 4; ++ni)
        bfv[ni] = *(const bf16x8*)(Bb + (size_t)(wc * 64 + ni * 16 + r) * 128 +
                                   ((kk * 64 + g * 16) ^ rx));
      for (int mi = 0; mi < 4; ++mi)
        for (int ni = 0; ni < 4; ++ni)
          acc[mi][ni] = mfma16(af[mi], bfv[ni], acc[mi][ni]);
    }
    __syncthreads();   // LDS free for next tile
  }

  if (OUT_MODE == 2) {
    // transposed epilogue -> vT[bh][d][s]; Cout = vT base, N=2048, M=4096.
    // tile[col][row] bf16 in LDS (pad to 136), then cooperative us8 row-writes.
    for (int mi = 0; mi < 4; ++mi)
      for (int ni = 0; ni < 4; ++ni) {
        int col = wc * 64 + ni * 16 + r;
        float bv = bias[bcol + col];
        int rowb = wr * 64 + mi * 16 + g * 4;
        for (int i = 0; i < 4; ++i)
          smem[col * 136 + rowb + i] = f2bf(acc[mi][ni][i] + bv);
      }
    __syncthreads();
    int col = tid >> 1, half = tid & 1;
    int bh = (int)(brow >> 11) * 16 + (int)(bcol >> 7);
    unsigned short* outp = (unsigned short*)Cout +
                           ((size_t)bh * 128 + col) * 2048 + (brow & 2047);
    for (int j = 0; j < 8; ++j) {
      int row0 = half * 64 + j * 8;
      *(us8*)(outp + row0) = *(const us8*)&smem[col * 136 + row0];
    }
    return;
  }

  for (int mi = 0; mi < 4; ++mi)
    for (int ni = 0; ni < 4; ++ni) {
      long col = bcol + wc * 64 + ni * 16 + r;
      float bv = bias ? bias[col] : 0.0f;
      long rowb = brow + wr * 64 + mi * 16 + g * 4;
      for (int i = 0; i < 4; ++i) {
        float v = acc[mi][ni][i] + bv;
        if (OUT_MODE == 1)
          ((float*)Cout)[(rowb + i) * (long)ldc + col] = v;
        else
          ((unsigned short*)Cout)[(rowb + i) * (long)ldc + col] = f2bf(v);
      }
    }
}

// ---------- rope: posqr[4096][1024] (per-head 64) and poskr[4096][64], vectorized ----------
__global__ void rope_kernel(const unsigned short* __restrict__ tmp_q,
                            const unsigned short* __restrict__ latext,
                            const float* __restrict__ costab,
                            const float* __restrict__ sintab,
                            unsigned short* __restrict__ posqr,
                            unsigned short* __restrict__ poskr) {
  int idx = blockIdx.x * 256 + threadIdx.x;  // 524288 posq + 32768 posk = 557056
  const unsigned short* src;
  unsigned short* dst;
  int s, dp0;
  if (idx < 524288) {
    int rowA = idx >> 7, rem = idx & 127;    // rem = h*8 + dpblk
    int h = rem >> 3;
    dp0 = (rem & 7) * 8;
    s = rowA & 2047;
    src = tmp_q + (size_t)rowA * 3072 + 2048 + h * 64;
    dst = posqr + (size_t)rowA * 1024 + h * 64 + dp0;
  } else if (idx < 557056) {
    int j = idx - 524288;
    int rowA = j >> 3;
    dp0 = (j & 7) * 8;
    s = rowA & 2047;
    src = latext + (size_t)rowA * 1664 + 1536;
    dst = poskr + (size_t)rowA * 64 + dp0;
  } else {
    return;
  }
  us8 x1 = *(const us8*)(src + dp0);
  us8 x2 = *(const us8*)(src + (dp0 ^ 32));
  int f0 = dp0 & 31;
  const float* cp = costab + s * 32 + f0;
  const float* sp = sintab + s * 32 + f0;
  bool low = dp0 < 32;
  us8 o;
  for (int e = 0; e < 8; ++e) {
    float a = b2f(x1[e]), b = b2f(x2[e]);
    float v = low ? (a * cp[e] - b * sp[e]) : (a * cp[e] + b * sp[e]);
    o[e] = f2bf(v);
  }
  *(us8*)dst = o;
}

// ---------- persistent causal flash attention, dynamic work-stealing ----------
// 1024 q-tiles (64 rows each), claimed longest-first: t -> qt = 31-(t>>5), bh = t&31.
// Reads K/Q nope from tmp_k/tmp_q, rope parts from poskr/posqr, V from vT.
// Writes normalized bf16 attn directly. T13 defer-max skips max-tree+rescale.
__global__ __launch_bounds__(256, 2)
void flash_kernel(const unsigned short* __restrict__ tmp_q,
                  const unsigned short* __restrict__ tmp_k,
                  const unsigned short* __restrict__ posqr,
                  const unsigned short* __restrict__ poskr,
                  const unsigned short* __restrict__ vT,
                  unsigned short* __restrict__ ob,
                  int* __restrict__ counter) {
  const int S = 2048;
  int tid = threadIdx.x, wave = tid >> 6, lane = tid & 63;
  int g = lane >> 4, r = lane & 15;
  const float sl2 = 1.44269504f / 13.8564064605510183f;  // log2e / sqrt(192)
  const float DEFER = 96.0f;                             // e-bound 2^10 in raw-score units

  __shared__ unsigned short Klds[32 * 192];   // swizzled: blk16 ^= row&7
  __shared__ unsigned short Vlds[128 * 32];   // swizzled: blk16 ^= row&3
  __shared__ unsigned short Plds[4][16][40];
  __shared__ int s_tile;
  char* Kb = (char*)Klds;
  char* Vb = (char*)Vlds;
  int rx7 = (r & 7) << 4, rx3 = (r & 3) << 4;

  for (;;) {
    if (tid == 0) s_tile = atomicAdd(counter, 1);
    __syncthreads();
    int t = s_tile;
    if (t >= 1024) return;
    int qt = 31 - (t >> 5), bh = t & 31;
    int b = bh >> 4, h = bh & 15;
    int qbase = qt * 64;
    int nchunk = 2 * (qt + 1);
    size_t rb = (size_t)b * 2048;

    const unsigned short* kpn = tmp_k + rb * 2048 + h * 128;  // row stride 2048
    const unsigned short* kpr = poskr + rb * 64;              // row stride 64
    const unsigned short* vp = vT + (size_t)bh * 128 * S;

    bf16x8 qf[6];
    {
      size_t qrowA = rb + qbase + wave * 16 + r;
      const unsigned short* qn = tmp_q + qrowA * 3072 + h * 128 + g * 8;
      for (int c = 0; c < 4; ++c) qf[c] = *(const bf16x8*)(qn + c * 32);
      const unsigned short* qr_ = posqr + qrowA * 1024 + h * 64 + g * 8;
      qf[4] = *(const bf16x8*)(qr_);
      qf[5] = *(const bf16x8*)(qr_ + 32);
    }

    f32x4 acc[8];
    for (int d = 0; d < 8; ++d) acc[d] = f32x4{0.f, 0.f, 0.f, 0.f};
    float m_r[4], l_r[4];
    for (int i = 0; i < 4; ++i) { m_r[i] = -3.0e38f; l_r[i] = 0.f; }

    // staging slot geometry
    int kn_row[2], kn_seg[2];
    for (int j = 0; j < 2; ++j) {
      int slot = j * 256 + tid;
      kn_row[j] = slot >> 4;
      kn_seg[j] = slot & 15;
    }
    int kr_row = tid >> 3, kr_seg = tid & 7;
    int v_row[2], v_seg[2];
    for (int j = 0; j < 2; ++j) {
      int slot = j * 256 + tid;
      v_row[j] = slot >> 2;
      v_seg[j] = slot & 3;
    }

    us8 kreg[2], krope, vreg[2];
    for (int j = 0; j < 2; ++j)
      kreg[j] = *(const us8*)(kpn + (size_t)kn_row[j] * 2048 + kn_seg[j] * 8);
    krope = *(const us8*)(kpr + (size_t)kr_row * 64 + kr_seg * 8);
    for (int j = 0; j < 2; ++j)
      vreg[j] = *(const us8*)(vp + (size_t)v_row[j] * S + v_seg[j] * 8);

    for (int ch = 0; ch < nchunk; ++ch) {
      for (int j = 0; j < 2; ++j)
        *(us8*)(Kb + (size_t)kn_row[j] * 384 +
                ((kn_seg[j] ^ (kn_row[j] & 7)) << 4)) = kreg[j];
      *(us8*)(Kb + (size_t)kr_row * 384 +
              (((16 + kr_seg) ^ (kr_row & 7)) << 4)) = krope;
      for (int j = 0; j < 2; ++j)
        *(us8*)(Vb + (size_t)v_row[j] * 64 +
                ((v_seg[j] ^ (v_row[j] & 3)) << 4)) = vreg[j];
      __syncthreads();
      if (ch + 1 < nchunk) {
        int kv1 = (ch + 1) * 32;
        for (int j = 0; j < 2; ++j)
          kreg[j] = *(const us8*)(kpn + (size_t)(kv1 + kn_row[j]) * 2048 + kn_seg[j] * 8);
        krope = *(const us8*)(kpr + (size_t)(kv1 + kr_row) * 64 + kr_seg * 8);
        for (int j = 0; j < 2; ++j)
          vreg[j] = *(const us8*)(vp + (size_t)v_row[j] * S + kv1 + v_seg[j] * 8);
      }
      int kv0 = ch * 32;

      f32x4 sc0 = {0.f, 0.f, 0.f, 0.f}, sc1 = {0.f, 0.f, 0.f, 0.f};
      __builtin_amdgcn_s_setprio(1);
      for (int c = 0; c < 6; ++c) {
        bf16x8 kf0 = *(const bf16x8*)(Kb + (size_t)r * 384 + (((c * 4 + g) << 4) ^ rx7));
        sc0 = mfma16(qf[c], kf0, sc0);
      }
      for (int c = 0; c < 6; ++c) {
        bf16x8 kf1 = *(const bf16x8*)(Kb + (size_t)(16 + r) * 384 + (((c * 4 + g) << 4) ^ rx7));
        sc1 = mfma16(qf[c], kf1, sc1);
      }
      __builtin_amdgcn_s_setprio(0);

      int kj0 = kv0 + r, kj1 = kv0 + 16 + r;
      int qi0 = qbase + wave * 16 + g * 4;
      for (int i = 0; i < 4; ++i) {
        if (kj0 > qi0 + i) sc0[i] = -1e30f;
        if (kj1 > qi0 + i) sc1[i] = -1e30f;
      }

      // T13 defer-max: skip max-tree + rescale when no row grew past m + DEFER
      float tl[4];
      bool ok = true;
      for (int i = 0; i < 4; ++i) {
        tl[i] = fmaxf(sc0[i], sc1[i]);
        ok = ok && (tl[i] - m_r[i] <= DEFER);
      }
      if (!__all(ok)) {
        for (int i = 0; i < 4; ++i) {
          float tm = tl[i];
          for (int off = 1; off < 16; off <<= 1) tm = fmaxf(tm, __shfl_xor(tm, off, 64));
          float mnew = fmaxf(m_r[i], tm);
          float corr = exp2f((m_r[i] - mnew) * sl2);
          l_r[i] *= corr;
          for (int d = 0; d < 8; ++d) acc[d][i] *= corr;
          m_r[i] = mnew;
        }
      }
      float p0[4], p1[4];
      for (int i = 0; i < 4; ++i) {
        float e0 = exp2f((sc0[i] - m_r[i]) * sl2);
        float e1 = exp2f((sc1[i] - m_r[i]) * sl2);
        float rs = e0 + e1;
        for (int off = 1; off < 16; off <<= 1) rs += __shfl_xor(rs, off, 64);
        l_r[i] += rs;
        p0[i] = e0;
        p1[i] = e1;
      }

      for (int i = 0; i < 4; ++i) {
        Plds[wave][g * 4 + i][r] = f2bf(p0[i]);
        Plds[wave][g * 4 + i][16 + r] = f2bf(p1[i]);
      }
      bf16x8 pa = *(const bf16x8*)&Plds[wave][r][g * 8];
      __builtin_amdgcn_s_setprio(1);
      for (int dt = 0; dt < 8; ++dt) {
        bf16x8 vf = *(const bf16x8*)(Vb + (size_t)(dt * 16 + r) * 64 + ((g << 4) ^ rx3));
        acc[dt] = mfma16(pa, vf, acc[dt]);
      }
      __builtin_amdgcn_s_setprio(0);
      __syncthreads();
    }

    // normalized store
    for (int i = 0; i < 4; ++i) {
      float inv = 1.0f / l_r[i];
      int row = qbase + wave * 16 + g * 4 + i;
      size_t base = (rb + row) * 2048 + h * 128;
      for (int dt = 0; dt < 8; ++dt)
        ob[base + dt * 16 + r] = f2bf(acc[dt][i] * inv);
    }
  }
}

// ---------- launcher ----------
extern "C" void kernel_launch(void* const* d_in, const int* in_sizes, int n_in,
                              void* d_out, int out_size, void* d_ws, size_t ws_size,
                              hipStream_t stream) {
  const float* x      = (const float*)d_in[0];
  const float* w_qkv  = (const float*)d_in[1];
  const float* b_qkv  = (const float*)d_in[2];
  const float* w_qup  = (const float*)d_in[3];
  const float* b_qup  = (const float*)d_in[4];
  const float* w_kup  = (const float*)d_in[5];
  const float* b_kup  = (const float*)d_in[6];
  const float* w_vup  = (const float*)d_in[7];
  const float* b_vup  = (const float*)d_in[8];
  const float* w_qpos = (const float*)d_in[9];
  const float* b_qpos = (const float*)d_in[10];
  const float* w_kpos = (const float*)d_in[11];
  const float* b_kpos = (const float*)d_in[12];
  const float* w_o    = (const float*)d_in[13];
  const float* b_o    = (const float*)d_in[14];
  (void)in_sizes; (void)n_in; (void)out_size; (void)ws_size;

  char* ws = (char*)d_ws;
  size_t off = 0;
  auto alloc = [&](size_t bytes) -> char* {
    char* p = ws + off;
    off += (bytes + 255) & ~(size_t)255;
    return p;
  };

  unsigned short* xb     = (unsigned short*)alloc(16777216);  // x bf16 [4096,2048]; reused as attn out
  unsigned short* wB1    = (unsigned short*)alloc(6815744);   // [1664,2048]
  unsigned short* wB2q   = (unsigned short*)alloc(3145728);   // [3072,512]
  unsigned short* wB2k   = (unsigned short*)alloc(2097152);   // [2048,512]
  unsigned short* wB2v   = (unsigned short*)alloc(2097152);   // [2048,512]
  unsigned short* wBo    = (unsigned short*)alloc(8388608);   // [2048,2048]
  float*          bias1  = (float*)alloc(1664 * 4);
  float*          bias2q = (float*)alloc(3072 * 4);
  float*          costab = (float*)alloc(262144);
  float*          sintab = (float*)alloc(262144);
  unsigned short* latext = (unsigned short*)alloc(13631488);  // [4096,1664]
  unsigned short* tmp_q  = (unsigned short*)alloc(25165824);  // [4096,3072]
  unsigned short* tmp_k  = (unsigned short*)alloc(16777216);  // [4096,2048]
  unsigned short* vTbuf  = (unsigned short*)alloc(16777216);  // [32,128,2048]
  unsigned short* posqr  = (unsigned short*)alloc(8388608);   // [4096,1024]
  unsigned short* poskr  = (unsigned short*)alloc(524288);    // [4096,64]
  int*            counter= (int*)alloc(256);
  unsigned short* attnb  = xb;                                // alias: xb dead after GEMM1

  // 1. misc prep
  prep_misc_kernel<<<512, 256, 0, stream>>>(b_qkv, b_kpos, b_qup, b_qpos,
                                            bias1, bias2q, costab, sintab,
                                            wB1 + (size_t)1600 * 2048);
  // 2. convert x
  convx_kernel<<<8192, 256, 0, stream>>>(x, xb, 2097152);
  // 3. weight transposes (fp32 -> bf16, [K,N] -> [N,K])
  tconv_kernel<<<dim3(48, 64), 256, 0, stream>>>(w_qkv, 1536, wB1, 2048);
  tconv_kernel<<<dim3(2, 64), 256, 0, stream>>>(w_kpos, 64, wB1 + (size_t)1536 * 2048, 2048);
  tconv_kernel<<<dim3(64, 16), 256, 0, stream>>>(w_qup, 2048, wB2q, 512);
  tconv_kernel<<<dim3(32, 16), 256, 0, stream>>>(w_qpos, 1024, wB2q + (size_t)2048 * 512, 512);
  tconv_kernel<<<dim3(64, 16), 256, 0, stream>>>(w_kup, 2048, wB2k, 512);
  tconv_kernel<<<dim3(64, 16), 256, 0, stream>>>(w_vup, 2048, wB2v, 512);
  tconv_kernel<<<dim3(64, 64), 256, 0, stream>>>(w_o, 2048, wBo, 2048);

  // 4. GEMM1: lat_ext[4096,1664] = xb @ wB1^T + bias1  (includes pos_k cols 1536..1599)
  gemm_bt_kernel<0><<<dim3(13, 32), 256, 0, stream>>>(xb, 2048, wB1, 2048,
                                                      latext, 1664, bias1, 2048);
  // 5. up-projections (K=512); v-up writes vT directly (transposed epilogue)
  gemm_bt_kernel<0><<<dim3(24, 32), 256, 0, stream>>>(latext, 1664, wB2q, 512,
                                                      tmp_q, 3072, bias2q, 512);
  gemm_bt_kernel<0><<<dim3(16, 32), 256, 0, stream>>>(latext + 512, 1664, wB2k, 512,
                                                      tmp_k, 2048, b_kup, 512);
  gemm_bt_kernel<2><<<dim3(16, 32), 256, 0, stream>>>(latext + 1024, 1664, wB2v, 512,
                                                      vTbuf, 2048, b_vup, 512);
  // 6. rope (posqr from tmp_q slice, poskr from latext slice)
  rope_kernel<<<2176, 256, 0, stream>>>(tmp_q, latext, costab, sintab, posqr, poskr);
  // 7. persistent flash attention (dynamic work-stealing) -> attnb
  hipMemsetAsync(counter, 0, 4, stream);
  flash_kernel<<<1536, 256, 0, stream>>>(tmp_q, tmp_k, posqr, poskr, vTbuf,
                                         attnb, counter);
  // 8. output projection (fp32 out + b_o)
  gemm_bt_kernel<1><<<dim3(16, 32), 256, 0, stream>>>(attnb, 2048, wBo, 2048,
                                                      d_out, 2048, b_o, 2048);
}